// Round 14
// baseline (687.434 us; speedup 1.0000x reference)
//
#include <hip/hip_runtime.h>
#include <math.h>

#define EMB 1024
#define FF  4096
#define NE  8
#define TTOK 8192

typedef __attribute__((ext_vector_type(4))) float  f32x4;
typedef __attribute__((ext_vector_type(8))) __bf16 bf16x8;
typedef __attribute__((ext_vector_type(4))) __bf16 bf16x4;

#define MAXROWS  18432   // 16384 assignments + 8*256 padding

// ---- ws layout (bytes) ----
#define WS_COUNTS  0
#define WS_CURSORS 1024
#define WS_SSUM    1056
#define WS_NTILES  2080
#define WS_BASE    2084
#define WS_TILE_E  2176
#define WS_TILE_RB 2816
#define WS_TKIDX   4096
#define WS_TKW     69632
#define WS_SLOT    135168
#define WS_TOKID   200704
#define WS_ROWW    274432
#define WS_BIG2    350208   // [W1T | xb | W2T | h | xg | (y1)]

#define SZ_W1T ((size_t)NE * EMB * FF * 2)   // 64 MB
#define SZ_W2T ((size_t)NE * EMB * FF * 2)   // 64 MB
#define SZ_XB  ((size_t)TTOK * EMB * 2)      // 16 MB
#define SZ_H   ((size_t)MAXROWS * FF * 2)    // 144 MB
#define SZ_XG  ((size_t)MAXROWS * EMB * 2)   // 36 MB
#define SZ_Y2  ((size_t)MAXROWS * EMB * 2)   // 36 MB (bf16 y)

__device__ inline f32x4 fzero() { f32x4 v = {0.f, 0.f, 0.f, 0.f}; return v; }

__device__ __forceinline__ void gl16(const void* g, void* l) {
    __builtin_amdgcn_global_load_lds(
        (const __attribute__((address_space(1))) void*)g,
        (__attribute__((address_space(3))) void*)l, 16, 0, 0);
}

// compiler-invisible LDS read: ds_read_b128 at 32-bit LDS byte addr + literal imm
#define DSR(dst, addr, off) \
    asm volatile("ds_read_b128 %0, %1 offset:" #off : "=v"(dst) : "v"(addr))

// fast erf-gelu (A&S 7.1.25, |erf err| <= 5e-4; bf16 h quantization dominates)
__device__ __forceinline__ float gelu_f(float v) {
    float u = fabsf(v) * 0.70710678118654752f;
    float p = 1.0f + u * (0.278393f + u * (0.230389f + u * (0.000972f + u * 0.078108f)));
    p = p * p; p = p * p;
    float er = 1.0f - 1.0f / p;
    float s = (v >= 0.0f) ? er : -er;
    return 0.5f * v * (1.0f + s);
}

// ---------------- gating (also emits xb = bf16(x)) ----------------
__global__ __launch_bounds__(256) void gate_kernel(
    const float* __restrict__ x, const float* __restrict__ gW, const float* __restrict__ gb,
    int* counts, float* ssum, int* tk_idx, float* tk_w, __bf16* __restrict__ xb)
{
    int wave = threadIdx.x >> 6;
    int lane = threadIdx.x & 63;
    int t = blockIdx.x * 4 + wave;

    float acc[NE];
#pragma unroll
    for (int e = 0; e < NE; e++) acc[e] = 0.f;

    const float* xr = x + (size_t)t * EMB;
    __bf16* xbr = xb + (size_t)t * EMB;
#pragma unroll
    for (int i = 0; i < 4; i++) {
        int d0 = i * 256 + lane * 4;
        f32x4 xv = *(const f32x4*)(xr + d0);
        bf16x4 cv;
#pragma unroll
        for (int q = 0; q < 4; q++) cv[q] = (__bf16)xv[q];
        *(bf16x4*)(xbr + d0) = cv;
#pragma unroll
        for (int j = 0; j < 4; j++) {
            const float* wrow = gW + (size_t)(d0 + j) * NE;
            float xs = xv[j];
#pragma unroll
            for (int e = 0; e < NE; e++) acc[e] += xs * wrow[e];
        }
    }
#pragma unroll
    for (int e = 0; e < NE; e++) {
#pragma unroll
        for (int off = 32; off; off >>= 1) acc[e] += __shfl_xor(acc[e], off, 64);
    }
    if (lane == 0) {
        float sc[NE];
        float m = -1e30f;
        for (int e = 0; e < NE; e++) { sc[e] = acc[e] + gb[e]; m = fmaxf(m, sc[e]); }
        float sum = 0.f;
        for (int e = 0; e < NE; e++) { sc[e] = expf(sc[e] - m); sum += sc[e]; }
        float inv = 1.f / sum;
        for (int e = 0; e < NE; e++) sc[e] *= inv;
        int i0 = 0; float s0 = sc[0];
        for (int e = 1; e < NE; e++) if (sc[e] > s0) { s0 = sc[e]; i0 = e; }
        int i1 = -1; float s1 = -1e30f;
        for (int e = 0; e < NE; e++) if (e != i0 && sc[e] > s1) { s1 = sc[e]; i1 = e; }
        float rn = 1.f / (s0 + s1);
        tk_idx[2 * t]     = i0;  tk_idx[2 * t + 1] = i1;
        tk_w[2 * t]       = s0 * rn;  tk_w[2 * t + 1] = s1 * rn;
        int slot = blockIdx.x & 31;
        atomicAdd(&counts[i0 * 32 + slot], 1);
        atomicAdd(&counts[i1 * 32 + slot], 1);
        for (int e = 0; e < NE; e++) atomicAdd(&ssum[e * 32 + slot], sc[e]);
    }
}

// ---------------- routing tables + aux (pad to 256-row tiles) ----------------
__global__ void route_build_kernel(const int* counts, const float* ssum,
                                   int* ntiles, int* base, int* tile_e, int* tile_rb,
                                   float* out_aux)
{
    if (threadIdx.x != 0 || blockIdx.x != 0) return;
    int total = 0, tiles = 0;
    float aux = 0.f;
    for (int e = 0; e < NE; e++) {
        int c = 0; float ss = 0.f;
        for (int j = 0; j < 32; j++) { c += counts[e * 32 + j]; ss += ssum[e * 32 + j]; }
        base[e] = total;
        int nt = (c + 255) >> 8;
        for (int i = 0; i < nt; i++) { tile_e[tiles] = e; tile_rb[tiles] = total + (i << 8); tiles++; }
        total += nt << 8;
        aux += ((float)c / (float)(TTOK * 2)) * (ss / (float)TTOK);
    }
    *ntiles = tiles;
    *out_aux = aux * (float)NE;
}

__global__ __launch_bounds__(256) void scatter_kernel(
    const int* __restrict__ tk_idx, const float* __restrict__ tk_w,
    const int* __restrict__ base, int* cursors, int* token_id, float* roww,
    int* slot_of)
{
    int t = blockIdx.x * 256 + threadIdx.x;
#pragma unroll
    for (int k = 0; k < 2; k++) {
        int e = tk_idx[2 * t + k];
        int pos = atomicAdd(&cursors[e], 1);
        int slot = base[e] + pos;
        token_id[slot] = t;
        roww[slot] = tk_w[2 * t + k];
        slot_of[2 * t + k] = slot;
    }
}

// ---------------- pack: xg[slot] = xb[token_id[slot]] (0 for pad) ----------------
__global__ __launch_bounds__(256) void pack_x_kernel(
    const __bf16* __restrict__ xb, const int* __restrict__ token_id,
    __bf16* __restrict__ xg)
{
    int tid = threadIdx.x;
    int slot = blockIdx.x * 2 + (tid >> 7);
    int off = (tid & 127) * 8;
    int tok = token_id[slot];
    uint4 v = {0u, 0u, 0u, 0u};
    if (tok >= 0) v = *(const uint4*)(xb + (size_t)tok * EMB + off);
    *(uint4*)(xg + (size_t)slot * EMB + off) = v;
}

// ---------------- combine (y in bf16) ----------------
__global__ __launch_bounds__(256) void combine_kernel(
    const __bf16* __restrict__ y0, const __bf16* __restrict__ y1, int nsplit,
    const int* __restrict__ slot_of,
    const int* __restrict__ tk_idx, const float* __restrict__ tk_w,
    const float* __restrict__ b2, float* __restrict__ out)
{
    int t = blockIdx.x;
    int dq = threadIdx.x * 4;
    int s0 = slot_of[2 * t], s1 = slot_of[2 * t + 1];
    int e0 = tk_idx[2 * t], e1 = tk_idx[2 * t + 1];
    float w0 = tk_w[2 * t], w1 = tk_w[2 * t + 1];
    bf16x4 va = *(const bf16x4*)(y0 + (size_t)s0 * EMB + dq);
    bf16x4 vb = *(const bf16x4*)(y0 + (size_t)s1 * EMB + dq);
    f32x4 ya, yb;
#pragma unroll
    for (int q = 0; q < 4; q++) { ya[q] = (float)va[q]; yb[q] = (float)vb[q]; }
    if (nsplit == 2) {
        bf16x4 za = *(const bf16x4*)(y1 + (size_t)s0 * EMB + dq);
        bf16x4 zb = *(const bf16x4*)(y1 + (size_t)s1 * EMB + dq);
#pragma unroll
        for (int q = 0; q < 4; q++) { ya[q] += (float)za[q]; yb[q] += (float)zb[q]; }
    }
    f32x4 ba = *(const f32x4*)(b2 + (size_t)e0 * EMB + dq);
    f32x4 bb = *(const f32x4*)(b2 + (size_t)e1 * EMB + dq);
    f32x4 r;
#pragma unroll
    for (int q = 0; q < 4; q++) r[q] = w0 * (ya[q] + ba[q]) + w1 * (yb[q] + bb[q]);
    *(f32x4*)(out + (size_t)t * EMB + dq) = r;
}

// merged transpose: flat grid; f>>13 selects W1 (0) / W2 (1)
__global__ __launch_bounds__(256) void transpose_cvt2_kernel(
    const float* __restrict__ W1, __bf16* __restrict__ W1T,
    const float* __restrict__ W2, __bf16* __restrict__ W2T)
{
    int f = blockIdx.x;
    int which = f >> 13; f &= 8191;
    int e = f >> 10; f &= 1023;
    int R, C, bx, by;
    const float* src; __bf16* dst;
    if (which == 0) { R = EMB; C = FF;  bx = f & 15; by = f >> 4; src = W1; dst = W1T; }
    else            { R = FF;  C = EMB; bx = f & 63; by = f >> 6; src = W2; dst = W2T; }
    src += (size_t)e * R * C;
    dst += (size_t)e * R * C;
    __shared__ __bf16 Ls[64 * 72];
    int t = threadIdx.x;
    int r0 = bx * 64, c0 = by * 64;
    int ri = t >> 4, cj = (t & 15) * 4;
#pragma unroll
    for (int p = 0; p < 4; p++) {
        int r = ri + p * 16;
        f32x4 v = *(const f32x4*)(src + (size_t)(r0 + r) * C + c0 + cj);
#pragma unroll
        for (int q = 0; q < 4; q++) Ls[(cj + q) * 72 + r] = (__bf16)v[q];
    }
    __syncthreads();
    int c = t >> 2, rq = (t & 3) * 16;
    bf16x8 a = *(bf16x8*)&Ls[c * 72 + rq];
    bf16x8 b = *(bf16x8*)&Ls[c * 72 + rq + 8];
    *(bf16x8*)(dst + (size_t)(c0 + c) * R + r0 + rq) = a;
    *(bf16x8*)(dst + (size_t)(c0 + c) * R + r0 + rq + 8) = b;
}

// ============================================================================
// Grouped GEMM, 3-blocks/CU variant: BM=128, BN=128, BK=32, 256 thr (4 waves
// 2Mx2N), wave tile 64x64 (acc[4][4]). 3 LDS bufs x 16KB = 48KB -> 3 blocks/CU
// (12 waves/CU, m97 occupancy) with 3 INDEPENDENT barrier domains per CU:
// co-resident blocks at different pipeline phases overlap each other's
// barrier/drain bubbles (m114 mechanism). Pipeline = r7's verified skeleton:
// 2 K-tiles in flight, counted vmcnt(4) (0 only at NT-2), 8 asm ds_read +
// 4 gl16 + lgkm(0)+sched_barrier + 16 MFMA + 1 barrier per K-tile.
// Same XOR chunk swizzle (slot = c ^ ((row>>1)&3), involution on src + read;
// 0 conflicts measured). LDS buf layout: A[128][32] @0, B[128][32] @8KB.
// Stage: wave w gl16#0 -> A rows w*16..+15 (elem w*512), #1 -> rows 64+w*16.
// ============================================================================

template <bool PACKED>
__global__ __launch_bounds__(256, 3) void gemm1_8p(
    const __bf16* __restrict__ xsrc, const __bf16* __restrict__ W1T,
    const float* __restrict__ b1,
    const int* __restrict__ token_id, const int* __restrict__ tile_e,
    const int* __restrict__ tile_rb, const int* __restrict__ ntiles,
    __bf16* __restrict__ h)
{
    extern __shared__ __bf16 lds[];   // 3 bufs x 8192 elems
    int flat = blockIdx.x;
    int c8 = flat & 7, r = flat >> 3;
    int sti = r >> 5, nb = r & 31;
    int st = c8 * 18 + sti;
    if (st >= *ntiles * 2) return;
    int e = tile_e[st >> 1];
    int rb = tile_rb[st >> 1] + (st & 1) * 128;
    int n0 = nb * 128;

    int tid = threadIdx.x, lane = tid & 63, wid = tid >> 6;
    int wr = wid >> 1, wc = wid & 1;
    int cl = lane & 15, cq = lane >> 4;

    // stage source: rows srow1 / srow1+64, swizzled chunk
    int srow1 = ((tid >> 6) << 4) | ((tid & 63) >> 2);
    int schunk = (tid & 3) ^ ((tid >> 3) & 3);
    const __bf16* ag[2];
#pragma unroll
    for (int hm = 0; hm < 2; hm++) {
        int row = srow1 + hm * 64;
        if (PACKED) {
            ag[hm] = xsrc + (size_t)(rb + row) * EMB + schunk * 8;
        } else {
            int tok = token_id[rb + row];
            if (tok < 0) tok = 0;
            ag[hm] = xsrc + (size_t)tok * EMB + schunk * 8;
        }
    }
    const __bf16* bg[2];
#pragma unroll
    for (int hn = 0; hn < 2; hn++)
        bg[hn] = W1T + ((size_t)e * FF + (size_t)(n0 + srow1 + hn * 64)) * EMB + schunk * 8;

    // stage dests (wave-uniform, elems within 8192-elem buf)
    int sdA0 = wid * 512, sdA1 = 2048 + wid * 512;
    int sdB0 = 4096 + wid * 512, sdB1 = 6144 + wid * 512;

    uint32_t lb = (uint32_t)(uintptr_t)(__attribute__((address_space(3))) __bf16*)lds;
    int xoffe = (cq ^ ((cl >> 1) & 3)) * 8;
    uint32_t ab0 = lb + 2u * (uint32_t)(wr * 2048 + cl * 32 + xoffe);
    uint32_t bb0 = lb + 2u * (uint32_t)(4096 + wc * 2048 + cl * 32 + xoffe);

    f32x4 acc[4][4];
#pragma unroll
    for (int i = 0; i < 4; i++)
#pragma unroll
        for (int j = 0; j < 4; j++) acc[i][j] = fzero();

    const int NT = EMB / 32;
    // prologue: stage tiles 0,1 into bufs 0,1
#pragma unroll
    for (int t0 = 0; t0 < 2; t0++) {
        __bf16* bp = lds + t0 * 8192;
        int k0 = t0 * 32;
        gl16(ag[0] + k0, bp + sdA0);
        gl16(ag[1] + k0, bp + sdA1);
        gl16(bg[0] + k0, bp + sdB0);
        gl16(bg[1] + k0, bp + sdB1);
    }
    asm volatile("s_waitcnt vmcnt(4)" ::: "memory");
    __builtin_amdgcn_s_barrier();

    int cb = 0;
#pragma unroll 1
    for (int t = 0; t < NT; t++) {
        uint32_t cboff = (uint32_t)cb * 16384u;
        uint32_t aaddr = ab0 + cboff, baddr = bb0 + cboff;
        bf16x8 b[4], a[4];
        DSR(b[0], baddr, 0);    DSR(b[1], baddr, 1024);
        DSR(b[2], baddr, 2048); DSR(b[3], baddr, 3072);
        DSR(a[0], aaddr, 0);    DSR(a[1], aaddr, 1024);
        DSR(a[2], aaddr, 2048); DSR(a[3], aaddr, 3072);

        int kt = t + 2;
        if (kt < NT) {
            int sb = cb + 2; if (sb >= 3) sb -= 3;
            __bf16* sp = lds + sb * 8192;
            int ko = kt * 32;
            gl16(ag[0] + ko, sp + sdA0);
            gl16(ag[1] + ko, sp + sdA1);
            gl16(bg[0] + ko, sp + sdB0);
            gl16(bg[1] + ko, sp + sdB1);
        }

        asm volatile("s_waitcnt lgkmcnt(0)" ::: "memory");
        __builtin_amdgcn_sched_barrier(0);
        __builtin_amdgcn_s_setprio(1);
#pragma unroll
        for (int mi = 0; mi < 4; mi++)
#pragma unroll
            for (int ni = 0; ni < 4; ni++)
                acc[mi][ni] = __builtin_amdgcn_mfma_f32_16x16x32_bf16(a[mi], b[ni], acc[mi][ni], 0, 0, 0);
        __builtin_amdgcn_s_setprio(0);

        if (t < NT - 2)       { asm volatile("s_waitcnt vmcnt(4)" ::: "memory"); }
        else if (t == NT - 2) { asm volatile("s_waitcnt vmcnt(0)" ::: "memory"); }
        if (t < NT - 1) __builtin_amdgcn_s_barrier();
        cb = cb + 1; if (cb >= 3) cb = 0;
    }

    // epilogue: bias + gelu -> bf16 h
    const float* b1g = b1 + (size_t)e * FF + n0;
#pragma unroll
    for (int mi = 0; mi < 4; mi++) {
#pragma unroll
        for (int ni = 0; ni < 4; ni++) {
            int col = wc * 64 + ni * 16 + cl;
            float bias = b1g[col];
#pragma unroll
            for (int j = 0; j < 4; j++) {
                int row = wr * 64 + mi * 16 + cq * 4 + j;
                float v = acc[mi][ni][j] + bias;
                h[(size_t)(rb + row) * FF + n0 + col] = (__bf16)gelu_f(v);
            }
        }
    }
}

__global__ __launch_bounds__(256, 3) void gemm2_8p(
    const __bf16* __restrict__ h, const __bf16* __restrict__ W2T,
    const int* __restrict__ tile_e, const int* __restrict__ tile_rb,
    const int* __restrict__ ntiles,
    __bf16* __restrict__ y0, __bf16* __restrict__ y1, int nsplit)
{
    extern __shared__ __bf16 lds[];
    int flat = blockIdx.x;
    int c8 = flat & 7, r = flat >> 3;
    int z = r / 144; int r144 = r - z * 144;
    int sti = r144 >> 3, nb = r144 & 7;
    int st = c8 * 18 + sti;
    if (st >= *ntiles * 2) return;
    int e = tile_e[st >> 1];
    int rb = tile_rb[st >> 1] + (st & 1) * 128;
    int n0 = nb * 128;
    int KC = FF / nsplit;
    int koff = z * KC;
    __bf16* y = z ? y1 : y0;

    int tid = threadIdx.x, lane = tid & 63, wid = tid >> 6;
    int wr = wid >> 1, wc = wid & 1;
    int cl = lane & 15, cq = lane >> 4;

    int srow1 = ((tid >> 6) << 4) | ((tid & 63) >> 2);
    int schunk = (tid & 3) ^ ((tid >> 3) & 3);
    const __bf16* ag[2];
#pragma unroll
    for (int hm = 0; hm < 2; hm++)
        ag[hm] = h + (size_t)(rb + srow1 + hm * 64) * FF + koff + schunk * 8;
    const __bf16* bg[2];
#pragma unroll
    for (int hn = 0; hn < 2; hn++)
        bg[hn] = W2T + ((size_t)e * EMB + (size_t)(n0 + srow1 + hn * 64)) * FF + koff + schunk * 8;

    int sdA0 = wid * 512, sdA1 = 2048 + wid * 512;
    int sdB0 = 4096 + wid * 512, sdB1 = 6144 + wid * 512;

    uint32_t lb = (uint32_t)(uintptr_t)(__attribute__((address_space(3))) __bf16*)lds;
    int xoffe = (cq ^ ((cl >> 1) & 3)) * 8;
    uint32_t ab0 = lb + 2u * (uint32_t)(wr * 2048 + cl * 32 + xoffe);
    uint32_t bb0 = lb + 2u * (uint32_t)(4096 + wc * 2048 + cl * 32 + xoffe);

    f32x4 acc[4][4];
#pragma unroll
    for (int i = 0; i < 4; i++)
#pragma unroll
        for (int j = 0; j < 4; j++) acc[i][j] = fzero();

    const int NT = KC / 32;
#pragma unroll
    for (int t0 = 0; t0 < 2; t0++) {
        __bf16* bp = lds + t0 * 8192;
        int k0 = t0 * 32;
        gl16(ag[0] + k0, bp + sdA0);
        gl16(ag[1] + k0, bp + sdA1);
        gl16(bg[0] + k0, bp + sdB0);
        gl16(bg[1] + k0, bp + sdB1);
    }
    asm volatile("s_waitcnt vmcnt(4)" ::: "memory");
    __builtin_amdgcn_s_barrier();

    int cb = 0;
#pragma unroll 1
    for (int t = 0; t < NT; t++) {
        uint32_t cboff = (uint32_t)cb * 16384u;
        uint32_t aaddr = ab0 + cboff, baddr = bb0 + cboff;
        bf16x8 b[4], a[4];
        DSR(b[0], baddr, 0);    DSR(b[1], baddr, 1024);
        DSR(b[2], baddr, 2048); DSR(b[3], baddr, 3072);
        DSR(a[0], aaddr, 0);    DSR(a[1], aaddr, 1024);
        DSR(a[2], aaddr, 2048); DSR(a[3], aaddr, 3072);

        int kt = t + 2;
        if (kt < NT) {
            int sb = cb + 2; if (sb >= 3) sb -= 3;
            __bf16* sp = lds + sb * 8192;
            int ko = kt * 32;
            gl16(ag[0] + ko, sp + sdA0);
            gl16(ag[1] + ko, sp + sdA1);
            gl16(bg[0] + ko, sp + sdB0);
            gl16(bg[1] + ko, sp + sdB1);
        }

        asm volatile("s_waitcnt lgkmcnt(0)" ::: "memory");
        __builtin_amdgcn_sched_barrier(0);
        __builtin_amdgcn_s_setprio(1);
#pragma unroll
        for (int mi = 0; mi < 4; mi++)
#pragma unroll
            for (int ni = 0; ni < 4; ni++)
                acc[mi][ni] = __builtin_amdgcn_mfma_f32_16x16x32_bf16(a[mi], b[ni], acc[mi][ni], 0, 0, 0);
        __builtin_amdgcn_s_setprio(0);

        if (t < NT - 2)       { asm volatile("s_waitcnt vmcnt(4)" ::: "memory"); }
        else if (t == NT - 2) { asm volatile("s_waitcnt vmcnt(0)" ::: "memory"); }
        if (t < NT - 1) __builtin_amdgcn_s_barrier();
        cb = cb + 1; if (cb >= 3) cb = 0;
    }

#pragma unroll
    for (int mi = 0; mi < 4; mi++) {
#pragma unroll
        for (int ni = 0; ni < 4; ni++) {
            int col = wc * 64 + ni * 16 + cl;
#pragma unroll
            for (int j = 0; j < 4; j++) {
                int row = wr * 64 + mi * 16 + cq * 4 + j;
                y[(size_t)(rb + row) * EMB + n0 + col] = (__bf16)acc[mi][ni][j];
            }
        }
    }
}

extern "C" void kernel_launch(void* const* d_in, const int* in_sizes, int n_in,
                              void* d_out, int out_size, void* d_ws, size_t ws_size,
                              hipStream_t stream)
{
    const float* x   = (const float*)d_in[0];
    const float* gW  = (const float*)d_in[1];
    const float* gb  = (const float*)d_in[2];
    const float* W1  = (const float*)d_in[3];
    const float* b1  = (const float*)d_in[4];
    const float* W2  = (const float*)d_in[5];
    const float* b2  = (const float*)d_in[6];
    float* out = (float*)d_out;

    char* ws = (char*)d_ws;
    int*   counts  = (int*)(ws + WS_COUNTS);
    int*   cursors = (int*)(ws + WS_CURSORS);
    float* ssum    = (float*)(ws + WS_SSUM);
    int*   ntiles  = (int*)(ws + WS_NTILES);
    int*   base    = (int*)(ws + WS_BASE);
    int*   tile_e  = (int*)(ws + WS_TILE_E);
    int*   tile_rb = (int*)(ws + WS_TILE_RB);
    int*   tk_idx  = (int*)(ws + WS_TKIDX);
    float* tk_w    = (float*)(ws + WS_TKW);
    int*   slot_of = (int*)(ws + WS_SLOT);
    int*   token_id= (int*)(ws + WS_TOKID);
    float* roww    = (float*)(ws + WS_ROWW);

    __bf16* W1T  = (__bf16*)(ws + WS_BIG2);
    __bf16* xb   = (__bf16*)(ws + WS_BIG2 + SZ_W1T);
    __bf16* W2T  = (__bf16*)(ws + WS_BIG2 + SZ_W1T + SZ_XB);
    __bf16* hbuf = (__bf16*)(ws + WS_BIG2 + SZ_W1T + SZ_XB + SZ_W2T);
    size_t fixedend = WS_BIG2 + SZ_W1T + SZ_XB + SZ_W2T;

    __bf16* y0 = (__bf16*)(ws + WS_BIG2);            // aliases W1T+xb (dead after gemm1)
    __bf16* xg = (__bf16*)(ws + fixedend + SZ_H);
    bool packed = (ws_size >= fixedend + SZ_H + SZ_XG);
    __bf16* y1 = (__bf16*)(ws + fixedend + SZ_H + (packed ? SZ_XG : 0));
    int nsplit = (ws_size >= fixedend + SZ_H + (packed ? SZ_XG : 0) + SZ_Y2) ? 2 : 1;

    hipFuncSetAttribute((const void*)gemm1_8p<true>,  hipFuncAttributeMaxDynamicSharedMemorySize, 49152);
    hipFuncSetAttribute((const void*)gemm1_8p<false>, hipFuncAttributeMaxDynamicSharedMemorySize, 49152);
    hipFuncSetAttribute((const void*)gemm2_8p, hipFuncAttributeMaxDynamicSharedMemorySize, 49152);

    hipMemsetAsync(ws + WS_COUNTS, 0, 2080, stream);
    hipMemsetAsync(ws + WS_TOKID, 0xFF, (size_t)MAXROWS * 4, stream);

    transpose_cvt2_kernel<<<16384, 256, 0, stream>>>(W1, W1T, W2, W2T);

    gate_kernel<<<TTOK / 4, 256, 0, stream>>>(x, gW, gb, counts, ssum, tk_idx, tk_w, xb);
    route_build_kernel<<<1, 64, 0, stream>>>(counts, ssum, ntiles, base, tile_e, tile_rb,
                                             out + (size_t)TTOK * EMB);
    scatter_kernel<<<TTOK / 256, 256, 0, stream>>>(tk_idx, tk_w, base, cursors, token_id, roww, slot_of);

    if (packed) {
        pack_x_kernel<<<MAXROWS / 2, 256, 0, stream>>>(xb, token_id, xg);
        gemm1_8p<true><<<8 * 18 * 32, 256, 49152, stream>>>(
            xg, W1T, b1, token_id, tile_e, tile_rb, ntiles, hbuf);
    } else {
        gemm1_8p<false><<<8 * 18 * 32, 256, 49152, stream>>>(
            xb, W1T, b1, token_id, tile_e, tile_rb, ntiles, hbuf);
    }
    gemm2_8p<<<8 * 18 * 8 * nsplit, 256, 49152, stream>>>(
        hbuf, W2T, tile_e, tile_rb, ntiles, y0, y1, nsplit);
    combine_kernel<<<TTOK, 256, 0, stream>>>(y0, y1, nsplit, slot_of, tk_idx, tk_w, b2, out);
}

// Round 15
// 685.594 us; speedup vs baseline: 1.0027x; 1.0027x over previous
//
#include <hip/hip_runtime.h>
#include <math.h>

#define EMB 1024
#define FF  4096
#define NE  8
#define TTOK 8192

typedef __attribute__((ext_vector_type(4))) float  f32x4;
typedef __attribute__((ext_vector_type(8))) __bf16 bf16x8;
typedef __attribute__((ext_vector_type(4))) __bf16 bf16x4;

#define MAXROWS  18432   // 16384 assignments + 8*256 padding

// ---- ws layout (bytes) ----
#define WS_COUNTS  0
#define WS_CURSORS 1024
#define WS_SSUM    1056
#define WS_NTILES  2080
#define WS_BASE    2084
#define WS_TILE_E  2176
#define WS_TILE_RB 2816
#define WS_TKIDX   4096
#define WS_TKW     69632
#define WS_SLOT    135168
#define WS_TOKID   200704
#define WS_ROWW    274432
#define WS_BIG2    350208   // [W1T | xb | W2T | h | xg | (y1)]

#define SZ_W1T ((size_t)NE * EMB * FF * 2)   // 64 MB
#define SZ_W2T ((size_t)NE * EMB * FF * 2)   // 64 MB
#define SZ_XB  ((size_t)TTOK * EMB * 2)      // 16 MB
#define SZ_H   ((size_t)MAXROWS * FF * 2)    // 144 MB
#define SZ_XG  ((size_t)MAXROWS * EMB * 2)   // 36 MB
#define SZ_Y2  ((size_t)MAXROWS * EMB * 2)   // 36 MB (bf16 y)

__device__ inline f32x4 fzero() { f32x4 v = {0.f, 0.f, 0.f, 0.f}; return v; }

__device__ __forceinline__ void gl16(const void* g, void* l) {
    __builtin_amdgcn_global_load_lds(
        (const __attribute__((address_space(1))) void*)g,
        (__attribute__((address_space(3))) void*)l, 16, 0, 0);
}

// compiler-invisible LDS read: ds_read_b128 at 32-bit LDS byte addr + literal imm
#define DSR(dst, addr, off) \
    asm volatile("ds_read_b128 %0, %1 offset:" #off : "=v"(dst) : "v"(addr))

// fast erf-gelu (A&S 7.1.25, |erf err| <= 5e-4; bf16 h quantization dominates)
__device__ __forceinline__ float gelu_f(float v) {
    float u = fabsf(v) * 0.70710678118654752f;
    float p = 1.0f + u * (0.278393f + u * (0.230389f + u * (0.000972f + u * 0.078108f)));
    p = p * p; p = p * p;
    float er = 1.0f - 1.0f / p;
    float s = (v >= 0.0f) ? er : -er;
    return 0.5f * v * (1.0f + s);
}

// ---------------- gating (also emits xb = bf16(x)) ----------------
__global__ __launch_bounds__(256) void gate_kernel(
    const float* __restrict__ x, const float* __restrict__ gW, const float* __restrict__ gb,
    int* counts, float* ssum, int* tk_idx, float* tk_w, __bf16* __restrict__ xb)
{
    int wave = threadIdx.x >> 6;
    int lane = threadIdx.x & 63;
    int t = blockIdx.x * 4 + wave;

    float acc[NE];
#pragma unroll
    for (int e = 0; e < NE; e++) acc[e] = 0.f;

    const float* xr = x + (size_t)t * EMB;
    __bf16* xbr = xb + (size_t)t * EMB;
#pragma unroll
    for (int i = 0; i < 4; i++) {
        int d0 = i * 256 + lane * 4;
        f32x4 xv = *(const f32x4*)(xr + d0);
        bf16x4 cv;
#pragma unroll
        for (int q = 0; q < 4; q++) cv[q] = (__bf16)xv[q];
        *(bf16x4*)(xbr + d0) = cv;
#pragma unroll
        for (int j = 0; j < 4; j++) {
            const float* wrow = gW + (size_t)(d0 + j) * NE;
            float xs = xv[j];
#pragma unroll
            for (int e = 0; e < NE; e++) acc[e] += xs * wrow[e];
        }
    }
#pragma unroll
    for (int e = 0; e < NE; e++) {
#pragma unroll
        for (int off = 32; off; off >>= 1) acc[e] += __shfl_xor(acc[e], off, 64);
    }
    if (lane == 0) {
        float sc[NE];
        float m = -1e30f;
        for (int e = 0; e < NE; e++) { sc[e] = acc[e] + gb[e]; m = fmaxf(m, sc[e]); }
        float sum = 0.f;
        for (int e = 0; e < NE; e++) { sc[e] = expf(sc[e] - m); sum += sc[e]; }
        float inv = 1.f / sum;
        for (int e = 0; e < NE; e++) sc[e] *= inv;
        int i0 = 0; float s0 = sc[0];
        for (int e = 1; e < NE; e++) if (sc[e] > s0) { s0 = sc[e]; i0 = e; }
        int i1 = -1; float s1 = -1e30f;
        for (int e = 0; e < NE; e++) if (e != i0 && sc[e] > s1) { s1 = sc[e]; i1 = e; }
        float rn = 1.f / (s0 + s1);
        tk_idx[2 * t]     = i0;  tk_idx[2 * t + 1] = i1;
        tk_w[2 * t]       = s0 * rn;  tk_w[2 * t + 1] = s1 * rn;
        int slot = blockIdx.x & 31;
        atomicAdd(&counts[i0 * 32 + slot], 1);
        atomicAdd(&counts[i1 * 32 + slot], 1);
        for (int e = 0; e < NE; e++) atomicAdd(&ssum[e * 32 + slot], sc[e]);
    }
}

// ---------------- routing tables + aux (pad to 256-row tiles) ----------------
__global__ void route_build_kernel(const int* counts, const float* ssum,
                                   int* ntiles, int* base, int* tile_e, int* tile_rb,
                                   float* out_aux)
{
    if (threadIdx.x != 0 || blockIdx.x != 0) return;
    int total = 0, tiles = 0;
    float aux = 0.f;
    for (int e = 0; e < NE; e++) {
        int c = 0; float ss = 0.f;
        for (int j = 0; j < 32; j++) { c += counts[e * 32 + j]; ss += ssum[e * 32 + j]; }
        base[e] = total;
        int nt = (c + 255) >> 8;
        for (int i = 0; i < nt; i++) { tile_e[tiles] = e; tile_rb[tiles] = total + (i << 8); tiles++; }
        total += nt << 8;
        aux += ((float)c / (float)(TTOK * 2)) * (ss / (float)TTOK);
    }
    *ntiles = tiles;
    *out_aux = aux * (float)NE;
}

__global__ __launch_bounds__(256) void scatter_kernel(
    const int* __restrict__ tk_idx, const float* __restrict__ tk_w,
    const int* __restrict__ base, int* cursors, int* token_id, float* roww,
    int* slot_of)
{
    int t = blockIdx.x * 256 + threadIdx.x;
#pragma unroll
    for (int k = 0; k < 2; k++) {
        int e = tk_idx[2 * t + k];
        int pos = atomicAdd(&cursors[e], 1);
        int slot = base[e] + pos;
        token_id[slot] = t;
        roww[slot] = tk_w[2 * t + k];
        slot_of[2 * t + k] = slot;
    }
}

// ---------------- pack: xg[slot] = xb[token_id[slot]] (0 for pad) ----------------
__global__ __launch_bounds__(256) void pack_x_kernel(
    const __bf16* __restrict__ xb, const int* __restrict__ token_id,
    __bf16* __restrict__ xg)
{
    int tid = threadIdx.x;
    int slot = blockIdx.x * 2 + (tid >> 7);
    int off = (tid & 127) * 8;
    int tok = token_id[slot];
    uint4 v = {0u, 0u, 0u, 0u};
    if (tok >= 0) v = *(const uint4*)(xb + (size_t)tok * EMB + off);
    *(uint4*)(xg + (size_t)slot * EMB + off) = v;
}

// ---------------- combine (y in bf16) ----------------
__global__ __launch_bounds__(256) void combine_kernel(
    const __bf16* __restrict__ y0, const __bf16* __restrict__ y1, int nsplit,
    const int* __restrict__ slot_of,
    const int* __restrict__ tk_idx, const float* __restrict__ tk_w,
    const float* __restrict__ b2, float* __restrict__ out)
{
    int t = blockIdx.x;
    int dq = threadIdx.x * 4;
    int s0 = slot_of[2 * t], s1 = slot_of[2 * t + 1];
    int e0 = tk_idx[2 * t], e1 = tk_idx[2 * t + 1];
    float w0 = tk_w[2 * t], w1 = tk_w[2 * t + 1];
    bf16x4 va = *(const bf16x4*)(y0 + (size_t)s0 * EMB + dq);
    bf16x4 vb = *(const bf16x4*)(y0 + (size_t)s1 * EMB + dq);
    f32x4 ya, yb;
#pragma unroll
    for (int q = 0; q < 4; q++) { ya[q] = (float)va[q]; yb[q] = (float)vb[q]; }
    if (nsplit == 2) {
        bf16x4 za = *(const bf16x4*)(y1 + (size_t)s0 * EMB + dq);
        bf16x4 zb = *(const bf16x4*)(y1 + (size_t)s1 * EMB + dq);
#pragma unroll
        for (int q = 0; q < 4; q++) { ya[q] += (float)za[q]; yb[q] += (float)zb[q]; }
    }
    f32x4 ba = *(const f32x4*)(b2 + (size_t)e0 * EMB + dq);
    f32x4 bb = *(const f32x4*)(b2 + (size_t)e1 * EMB + dq);
    f32x4 r;
#pragma unroll
    for (int q = 0; q < 4; q++) r[q] = w0 * (ya[q] + ba[q]) + w1 * (yb[q] + bb[q]);
    *(f32x4*)(out + (size_t)t * EMB + dq) = r;
}

// merged transpose: flat grid; f>>13 selects W1 (0) / W2 (1)
__global__ __launch_bounds__(256) void transpose_cvt2_kernel(
    const float* __restrict__ W1, __bf16* __restrict__ W1T,
    const float* __restrict__ W2, __bf16* __restrict__ W2T)
{
    int f = blockIdx.x;
    int which = f >> 13; f &= 8191;
    int e = f >> 10; f &= 1023;
    int R, C, bx, by;
    const float* src; __bf16* dst;
    if (which == 0) { R = EMB; C = FF;  bx = f & 15; by = f >> 4; src = W1; dst = W1T; }
    else            { R = FF;  C = EMB; bx = f & 63; by = f >> 6; src = W2; dst = W2T; }
    src += (size_t)e * R * C;
    dst += (size_t)e * R * C;
    __shared__ __bf16 Ls[64 * 72];
    int t = threadIdx.x;
    int r0 = bx * 64, c0 = by * 64;
    int ri = t >> 4, cj = (t & 15) * 4;
#pragma unroll
    for (int p = 0; p < 4; p++) {
        int r = ri + p * 16;
        f32x4 v = *(const f32x4*)(src + (size_t)(r0 + r) * C + c0 + cj);
#pragma unroll
        for (int q = 0; q < 4; q++) Ls[(cj + q) * 72 + r] = (__bf16)v[q];
    }
    __syncthreads();
    int c = t >> 2, rq = (t & 3) * 16;
    bf16x8 a = *(bf16x8*)&Ls[c * 72 + rq];
    bf16x8 b = *(bf16x8*)&Ls[c * 72 + rq + 8];
    *(bf16x8*)(dst + (size_t)(c0 + c) * R + r0 + rq) = a;
    *(bf16x8*)(dst + (size_t)(c0 + c) * R + r0 + rq + 8) = b;
}

// ============================================================================
// gemm1 (r14 winner + L2-blocked grid): BM=128, BN=128, BK=32, 256 thr
// (4 waves 2x2, wave tile 64x64, acc[4][4]). 3 LDS bufs x 16KB = 48KB ->
// 3 blocks/CU, 3 independent barrier domains (m114 overlap). Grid ordering
// within XCD: nbg outer (4 groups of 8 n-panels), sti middle, nbi inner ->
// inner working set = 8 B panels (2MB) + A subtile (256KB) < 4MB L2, so
// B is L2-resident across the 18-subtile sweep (FETCH ~halved vs r14).
// Pipeline verbatim r14 (counted vmcnt(4), XOR chunk swizzle, 0 conflicts).
// ============================================================================

template <bool PACKED>
__global__ __launch_bounds__(256, 3) void gemm1_8p(
    const __bf16* __restrict__ xsrc, const __bf16* __restrict__ W1T,
    const float* __restrict__ b1,
    const int* __restrict__ token_id, const int* __restrict__ tile_e,
    const int* __restrict__ tile_rb, const int* __restrict__ ntiles,
    __bf16* __restrict__ h)
{
    extern __shared__ __bf16 lds[];   // 3 bufs x 8192 elems
    int flat = blockIdx.x;
    int c8 = flat & 7, r = flat >> 3;
    int nbg = r / 144;                 // 0..3
    int rem = r - nbg * 144;
    int sti = rem >> 3;                // 0..17
    int nb  = (nbg << 3) | (rem & 7);  // 0..31
    int st = c8 * 18 + sti;
    if (st >= *ntiles * 2) return;
    int e = tile_e[st >> 1];
    int rb = tile_rb[st >> 1] + (st & 1) * 128;
    int n0 = nb * 128;

    int tid = threadIdx.x, lane = tid & 63, wid = tid >> 6;
    int wr = wid >> 1, wc = wid & 1;
    int cl = lane & 15, cq = lane >> 4;

    int srow1 = ((tid >> 6) << 4) | ((tid & 63) >> 2);
    int schunk = (tid & 3) ^ ((tid >> 3) & 3);
    const __bf16* ag[2];
#pragma unroll
    for (int hm = 0; hm < 2; hm++) {
        int row = srow1 + hm * 64;
        if (PACKED) {
            ag[hm] = xsrc + (size_t)(rb + row) * EMB + schunk * 8;
        } else {
            int tok = token_id[rb + row];
            if (tok < 0) tok = 0;
            ag[hm] = xsrc + (size_t)tok * EMB + schunk * 8;
        }
    }
    const __bf16* bg[2];
#pragma unroll
    for (int hn = 0; hn < 2; hn++)
        bg[hn] = W1T + ((size_t)e * FF + (size_t)(n0 + srow1 + hn * 64)) * EMB + schunk * 8;

    int sdA0 = wid * 512, sdA1 = 2048 + wid * 512;
    int sdB0 = 4096 + wid * 512, sdB1 = 6144 + wid * 512;

    uint32_t lb = (uint32_t)(uintptr_t)(__attribute__((address_space(3))) __bf16*)lds;
    int xoffe = (cq ^ ((cl >> 1) & 3)) * 8;
    uint32_t ab0 = lb + 2u * (uint32_t)(wr * 2048 + cl * 32 + xoffe);
    uint32_t bb0 = lb + 2u * (uint32_t)(4096 + wc * 2048 + cl * 32 + xoffe);

    f32x4 acc[4][4];
#pragma unroll
    for (int i = 0; i < 4; i++)
#pragma unroll
        for (int j = 0; j < 4; j++) acc[i][j] = fzero();

    const int NT = EMB / 32;
#pragma unroll
    for (int t0 = 0; t0 < 2; t0++) {
        __bf16* bp = lds + t0 * 8192;
        int k0 = t0 * 32;
        gl16(ag[0] + k0, bp + sdA0);
        gl16(ag[1] + k0, bp + sdA1);
        gl16(bg[0] + k0, bp + sdB0);
        gl16(bg[1] + k0, bp + sdB1);
    }
    asm volatile("s_waitcnt vmcnt(4)" ::: "memory");
    __builtin_amdgcn_s_barrier();

    int cb = 0;
#pragma unroll 1
    for (int t = 0; t < NT; t++) {
        uint32_t cboff = (uint32_t)cb * 16384u;
        uint32_t aaddr = ab0 + cboff, baddr = bb0 + cboff;
        bf16x8 b[4], a[4];
        DSR(b[0], baddr, 0);    DSR(b[1], baddr, 1024);
        DSR(b[2], baddr, 2048); DSR(b[3], baddr, 3072);
        DSR(a[0], aaddr, 0);    DSR(a[1], aaddr, 1024);
        DSR(a[2], aaddr, 2048); DSR(a[3], aaddr, 3072);

        int kt = t + 2;
        if (kt < NT) {
            int sb = cb + 2; if (sb >= 3) sb -= 3;
            __bf16* sp = lds + sb * 8192;
            int ko = kt * 32;
            gl16(ag[0] + ko, sp + sdA0);
            gl16(ag[1] + ko, sp + sdA1);
            gl16(bg[0] + ko, sp + sdB0);
            gl16(bg[1] + ko, sp + sdB1);
        }

        asm volatile("s_waitcnt lgkmcnt(0)" ::: "memory");
        __builtin_amdgcn_sched_barrier(0);
        __builtin_amdgcn_s_setprio(1);
#pragma unroll
        for (int mi = 0; mi < 4; mi++)
#pragma unroll
            for (int ni = 0; ni < 4; ni++)
                acc[mi][ni] = __builtin_amdgcn_mfma_f32_16x16x32_bf16(a[mi], b[ni], acc[mi][ni], 0, 0, 0);
        __builtin_amdgcn_s_setprio(0);

        if (t < NT - 2)       { asm volatile("s_waitcnt vmcnt(4)" ::: "memory"); }
        else if (t == NT - 2) { asm volatile("s_waitcnt vmcnt(0)" ::: "memory"); }
        if (t < NT - 1) __builtin_amdgcn_s_barrier();
        cb = cb + 1; if (cb >= 3) cb = 0;
    }

    const float* b1g = b1 + (size_t)e * FF + n0;
#pragma unroll
    for (int mi = 0; mi < 4; mi++) {
#pragma unroll
        for (int ni = 0; ni < 4; ni++) {
            int col = wc * 64 + ni * 16 + cl;
            float bias = b1g[col];
#pragma unroll
            for (int j = 0; j < 4; j++) {
                int row = wr * 64 + mi * 16 + cq * 4 + j;
                float v = acc[mi][ni][j] + bias;
                h[(size_t)(rb + row) * FF + n0 + col] = (__bf16)gelu_f(v);
            }
        }
    }
}

// ============================================================================
// gemm2 (r13 green 256x256 8-wave kernel, verbatim): BM=256, BN=256, BK=32,
// 512 thr, wave tile 128x64 (acc[8][4]), 4 LDS bufs x 32KB, counted vmcnt(8).
// ============================================================================
__global__ __launch_bounds__(512, 2) void gemm2_8p(
    const __bf16* __restrict__ h, const __bf16* __restrict__ W2T,
    const int* __restrict__ tile_e, const int* __restrict__ tile_rb,
    const int* __restrict__ ntiles,
    __bf16* __restrict__ y0, __bf16* __restrict__ y1, int nsplit)
{
    extern __shared__ __bf16 lds[];
    int flat = blockIdx.x;
    int c8 = flat & 7, r = flat >> 3;
    int z = r / 36; int r36 = r - z * 36;
    int mti = r36 >> 2, nb = r36 & 3;
    int mt = c8 * 9 + mti;
    if (mt >= *ntiles) return;
    int e = tile_e[mt], rb = tile_rb[mt];
    int n0 = nb * 256;
    int KC = FF / nsplit;
    int koff = z * KC;
    __bf16* y = z ? y1 : y0;

    int tid = threadIdx.x, lane = tid & 63, wid = tid >> 6;
    int wr = wid >> 2, wc = wid & 3;
    int cl = lane & 15, cq = lane >> 4;

    int srow = tid >> 2;
    int schunk = (tid & 3) ^ ((tid >> 3) & 3);
    const __bf16* ag[2];
#pragma unroll
    for (int hm = 0; hm < 2; hm++)
        ag[hm] = h + (size_t)(rb + hm * 128 + srow) * FF + koff + schunk * 8;
    const __bf16* bg[2];
#pragma unroll
    for (int hn = 0; hn < 2; hn++)
        bg[hn] = W2T + ((size_t)e * EMB + (size_t)(n0 + hn * 128 + srow)) * FF + koff + schunk * 8;

    int sdA0 = wid * 512, sdA1 = 4096 + wid * 512;
    int sdB0 = 8192 + wid * 512, sdB1 = 12288 + wid * 512;

    uint32_t lb = (uint32_t)(uintptr_t)(__attribute__((address_space(3))) __bf16*)lds;
    int xoffe = (cq ^ ((cl >> 1) & 3)) * 8;
    uint32_t ab0 = lb + 2u * (uint32_t)(wr * 4096 + cl * 32 + xoffe);
    uint32_t bb0 = lb + 2u * (uint32_t)(8192 + (wc >> 1) * 4096 + ((wc & 1) * 64 + cl) * 32 + xoffe);

    f32x4 acc[8][4];
#pragma unroll
    for (int i = 0; i < 8; i++)
#pragma unroll
        for (int j = 0; j < 4; j++) acc[i][j] = fzero();

    const int NT = KC / 32;
#pragma unroll
    for (int t0 = 0; t0 < 3; t0++) {
        __bf16* bp = lds + t0 * 16384;
        int k0 = t0 * 32;
        gl16(ag[0] + k0, bp + sdA0);
        gl16(ag[1] + k0, bp + sdA1);
        gl16(bg[0] + k0, bp + sdB0);
        gl16(bg[1] + k0, bp + sdB1);
    }
    asm volatile("s_waitcnt vmcnt(8)" ::: "memory");
    __builtin_amdgcn_s_barrier();

#pragma unroll 1
    for (int t = 0; t < NT; t++) {
        uint32_t cboff = (uint32_t)(t & 3) * 32768u;
        uint32_t aaddr = ab0 + cboff, baddr = bb0 + cboff;
        bf16x8 b[4], a[8];
        DSR(b[0], baddr, 0);    DSR(b[1], baddr, 1024);
        DSR(b[2], baddr, 2048); DSR(b[3], baddr, 3072);
        DSR(a[0], aaddr, 0);    DSR(a[1], aaddr, 1024);
        DSR(a[2], aaddr, 2048); DSR(a[3], aaddr, 3072);
        DSR(a[4], aaddr, 4096); DSR(a[5], aaddr, 5120);
        DSR(a[6], aaddr, 6144); DSR(a[7], aaddr, 7168);

        int kt = t + 3;
        if (kt < NT) {
            __bf16* sp = lds + (kt & 3) * 16384;
            int ko = kt * 32;
            gl16(ag[0] + ko, sp + sdA0);
            gl16(ag[1] + ko, sp + sdA1);
            gl16(bg[0] + ko, sp + sdB0);
            gl16(bg[1] + ko, sp + sdB1);
        }

        asm volatile("s_waitcnt lgkmcnt(0)" ::: "memory");
        __builtin_amdgcn_sched_barrier(0);
        __builtin_amdgcn_s_setprio(1);
#pragma unroll
        for (int mi = 0; mi < 8; mi++)
#pragma unroll
            for (int ni = 0; ni < 4; ni++)
                acc[mi][ni] = __builtin_amdgcn_mfma_f32_16x16x32_bf16(a[mi], b[ni], acc[mi][ni], 0, 0, 0);
        __builtin_amdgcn_s_setprio(0);

        if (t < NT - 3)       { asm volatile("s_waitcnt vmcnt(8)" ::: "memory"); }
        else if (t == NT - 3) { asm volatile("s_waitcnt vmcnt(4)" ::: "memory"); }
        else if (t == NT - 2) { asm volatile("s_waitcnt vmcnt(0)" ::: "memory"); }
        if (t < NT - 1) __builtin_amdgcn_s_barrier();
    }

#pragma unroll
    for (int mi = 0; mi < 8; mi++) {
#pragma unroll
        for (int ni = 0; ni < 4; ni++) {
            int col = wc * 64 + ni * 16 + cl;
#pragma unroll
            for (int j = 0; j < 4; j++) {
                int row = wr * 128 + mi * 16 + cq * 4 + j;
                y[(size_t)(rb + row) * EMB + n0 + col] = (__bf16)acc[mi][ni][j];
            }
        }
    }
}

extern "C" void kernel_launch(void* const* d_in, const int* in_sizes, int n_in,
                              void* d_out, int out_size, void* d_ws, size_t ws_size,
                              hipStream_t stream)
{
    const float* x   = (const float*)d_in[0];
    const float* gW  = (const float*)d_in[1];
    const float* gb  = (const float*)d_in[2];
    const float* W1  = (const float*)d_in[3];
    const float* b1  = (const float*)d_in[4];
    const float* W2  = (const float*)d_in[5];
    const float* b2  = (const float*)d_in[6];
    float* out = (float*)d_out;

    char* ws = (char*)d_ws;
    int*   counts  = (int*)(ws + WS_COUNTS);
    int*   cursors = (int*)(ws + WS_CURSORS);
    float* ssum    = (float*)(ws + WS_SSUM);
    int*   ntiles  = (int*)(ws + WS_NTILES);
    int*   base    = (int*)(ws + WS_BASE);
    int*   tile_e  = (int*)(ws + WS_TILE_E);
    int*   tile_rb = (int*)(ws + WS_TILE_RB);
    int*   tk_idx  = (int*)(ws + WS_TKIDX);
    float* tk_w    = (float*)(ws + WS_TKW);
    int*   slot_of = (int*)(ws + WS_SLOT);
    int*   token_id= (int*)(ws + WS_TOKID);
    float* roww    = (float*)(ws + WS_ROWW);

    __bf16* W1T  = (__bf16*)(ws + WS_BIG2);
    __bf16* xb   = (__bf16*)(ws + WS_BIG2 + SZ_W1T);
    __bf16* W2T  = (__bf16*)(ws + WS_BIG2 + SZ_W1T + SZ_XB);
    __bf16* hbuf = (__bf16*)(ws + WS_BIG2 + SZ_W1T + SZ_XB + SZ_W2T);
    size_t fixedend = WS_BIG2 + SZ_W1T + SZ_XB + SZ_W2T;

    __bf16* y0 = (__bf16*)(ws + WS_BIG2);            // aliases W1T+xb (dead after gemm1)
    __bf16* xg = (__bf16*)(ws + fixedend + SZ_H);
    bool packed = (ws_size >= fixedend + SZ_H + SZ_XG);
    __bf16* y1 = (__bf16*)(ws + fixedend + SZ_H + (packed ? SZ_XG : 0));
    int nsplit = (ws_size >= fixedend + SZ_H + (packed ? SZ_XG : 0) + SZ_Y2) ? 2 : 1;

    hipFuncSetAttribute((const void*)gemm1_8p<true>,  hipFuncAttributeMaxDynamicSharedMemorySize, 49152);
    hipFuncSetAttribute((const void*)gemm1_8p<false>, hipFuncAttributeMaxDynamicSharedMemorySize, 49152);
    hipFuncSetAttribute((const void*)gemm2_8p, hipFuncAttributeMaxDynamicSharedMemorySize, 131072);

    hipMemsetAsync(ws + WS_COUNTS, 0, 2080, stream);
    hipMemsetAsync(ws + WS_TOKID, 0xFF, (size_t)MAXROWS * 4, stream);

    transpose_cvt2_kernel<<<16384, 256, 0, stream>>>(W1, W1T, W2, W2T);

    gate_kernel<<<TTOK / 4, 256, 0, stream>>>(x, gW, gb, counts, ssum, tk_idx, tk_w, xb);
    route_build_kernel<<<1, 64, 0, stream>>>(counts, ssum, ntiles, base, tile_e, tile_rb,
                                             out + (size_t)TTOK * EMB);
    scatter_kernel<<<TTOK / 256, 256, 0, stream>>>(tk_idx, tk_w, base, cursors, token_id, roww, slot_of);

    if (packed) {
        pack_x_kernel<<<MAXROWS / 2, 256, 0, stream>>>(xb, token_id, xg);
        gemm1_8p<true><<<8 * 18 * 32, 256, 49152, stream>>>(
            xg, W1T, b1, token_id, tile_e, tile_rb, ntiles, hbuf);
    } else {
        gemm1_8p<false><<<8 * 18 * 32, 256, 49152, stream>>>(
            xb, W1T, b1, token_id, tile_e, tile_rb, ntiles, hbuf);
    }
    gemm2_8p<<<8 * 9 * 4 * nsplit, 512, 131072, stream>>>(
        hbuf, W2T, tile_e, tile_rb, ntiles, y0, y1, nsplit);
    combine_kernel<<<TTOK, 256, 0, stream>>>(y0, y1, nsplit, slot_of, tk_idx, tk_w, b2, out);
}

// Round 16
// 679.239 us; speedup vs baseline: 1.0121x; 1.0094x over previous
//
#include <hip/hip_runtime.h>
#include <math.h>

#define EMB 1024
#define FF  4096
#define NE  8
#define TTOK 8192

typedef __attribute__((ext_vector_type(4))) float  f32x4;
typedef __attribute__((ext_vector_type(8))) __bf16 bf16x8;
typedef __attribute__((ext_vector_type(4))) __bf16 bf16x4;

#define MAXROWS  18432   // 16384 assignments + 8*256 padding

// ---- ws layout (bytes) ----
#define WS_COUNTS  0
#define WS_CURSORS 1024
#define WS_SSUM    1056
#define WS_NTILES  2080
#define WS_BASE    2084
#define WS_TILE_E  2176
#define WS_TILE_RB 2816
#define WS_TKIDX   4096
#define WS_TKW     69632
#define WS_SLOT    135168
#define WS_TOKID   200704
#define WS_ROWW    274432
#define WS_BIG2    350208   // [W1T | xb | W2T | h | xg | (y1)]

#define SZ_W1T ((size_t)NE * EMB * FF * 2)   // 64 MB
#define SZ_W2T ((size_t)NE * EMB * FF * 2)   // 64 MB
#define SZ_XB  ((size_t)TTOK * EMB * 2)      // 16 MB
#define SZ_H   ((size_t)MAXROWS * FF * 2)    // 144 MB
#define SZ_XG  ((size_t)MAXROWS * EMB * 2)   // 36 MB
#define SZ_Y2  ((size_t)MAXROWS * EMB * 2)   // 36 MB (bf16 y)

__device__ inline f32x4 fzero() { f32x4 v = {0.f, 0.f, 0.f, 0.f}; return v; }

__device__ __forceinline__ void gl16(const void* g, void* l) {
    __builtin_amdgcn_global_load_lds(
        (const __attribute__((address_space(1))) void*)g,
        (__attribute__((address_space(3))) void*)l, 16, 0, 0);
}

// compiler-invisible LDS read: ds_read_b128 at 32-bit LDS byte addr + literal imm
#define DSR(dst, addr, off) \
    asm volatile("ds_read_b128 %0, %1 offset:" #off : "=v"(dst) : "v"(addr))

// fast erf-gelu (A&S 7.1.25, |erf err| <= 5e-4; bf16 h quantization dominates)
__device__ __forceinline__ float gelu_f(float v) {
    float u = fabsf(v) * 0.70710678118654752f;
    float p = 1.0f + u * (0.278393f + u * (0.230389f + u * (0.000972f + u * 0.078108f)));
    p = p * p; p = p * p;
    float er = 1.0f - 1.0f / p;
    float s = (v >= 0.0f) ? er : -er;
    return 0.5f * v * (1.0f + s);
}

// ---------------- gating (also emits xb = bf16(x)) ----------------
__global__ __launch_bounds__(256) void gate_kernel(
    const float* __restrict__ x, const float* __restrict__ gW, const float* __restrict__ gb,
    int* counts, float* ssum, int* tk_idx, float* tk_w, __bf16* __restrict__ xb)
{
    int wave = threadIdx.x >> 6;
    int lane = threadIdx.x & 63;
    int t = blockIdx.x * 4 + wave;

    float acc[NE];
#pragma unroll
    for (int e = 0; e < NE; e++) acc[e] = 0.f;

    const float* xr = x + (size_t)t * EMB;
    __bf16* xbr = xb + (size_t)t * EMB;
#pragma unroll
    for (int i = 0; i < 4; i++) {
        int d0 = i * 256 + lane * 4;
        f32x4 xv = *(const f32x4*)(xr + d0);
        bf16x4 cv;
#pragma unroll
        for (int q = 0; q < 4; q++) cv[q] = (__bf16)xv[q];
        *(bf16x4*)(xbr + d0) = cv;
#pragma unroll
        for (int j = 0; j < 4; j++) {
            const float* wrow = gW + (size_t)(d0 + j) * NE;
            float xs = xv[j];
#pragma unroll
            for (int e = 0; e < NE; e++) acc[e] += xs * wrow[e];
        }
    }
#pragma unroll
    for (int e = 0; e < NE; e++) {
#pragma unroll
        for (int off = 32; off; off >>= 1) acc[e] += __shfl_xor(acc[e], off, 64);
    }
    if (lane == 0) {
        float sc[NE];
        float m = -1e30f;
        for (int e = 0; e < NE; e++) { sc[e] = acc[e] + gb[e]; m = fmaxf(m, sc[e]); }
        float sum = 0.f;
        for (int e = 0; e < NE; e++) { sc[e] = expf(sc[e] - m); sum += sc[e]; }
        float inv = 1.f / sum;
        for (int e = 0; e < NE; e++) sc[e] *= inv;
        int i0 = 0; float s0 = sc[0];
        for (int e = 1; e < NE; e++) if (sc[e] > s0) { s0 = sc[e]; i0 = e; }
        int i1 = -1; float s1 = -1e30f;
        for (int e = 0; e < NE; e++) if (e != i0 && sc[e] > s1) { s1 = sc[e]; i1 = e; }
        float rn = 1.f / (s0 + s1);
        tk_idx[2 * t]     = i0;  tk_idx[2 * t + 1] = i1;
        tk_w[2 * t]       = s0 * rn;  tk_w[2 * t + 1] = s1 * rn;
        int slot = blockIdx.x & 31;
        atomicAdd(&counts[i0 * 32 + slot], 1);
        atomicAdd(&counts[i1 * 32 + slot], 1);
        for (int e = 0; e < NE; e++) atomicAdd(&ssum[e * 32 + slot], sc[e]);
    }
}

// ---------------- routing tables + aux (pad to 256-row tiles) ----------------
__global__ void route_build_kernel(const int* counts, const float* ssum,
                                   int* ntiles, int* base, int* tile_e, int* tile_rb,
                                   float* out_aux)
{
    if (threadIdx.x != 0 || blockIdx.x != 0) return;
    int total = 0, tiles = 0;
    float aux = 0.f;
    for (int e = 0; e < NE; e++) {
        int c = 0; float ss = 0.f;
        for (int j = 0; j < 32; j++) { c += counts[e * 32 + j]; ss += ssum[e * 32 + j]; }
        base[e] = total;
        int nt = (c + 255) >> 8;
        for (int i = 0; i < nt; i++) { tile_e[tiles] = e; tile_rb[tiles] = total + (i << 8); tiles++; }
        total += nt << 8;
        aux += ((float)c / (float)(TTOK * 2)) * (ss / (float)TTOK);
    }
    *ntiles = tiles;
    *out_aux = aux * (float)NE;
}

__global__ __launch_bounds__(256) void scatter_kernel(
    const int* __restrict__ tk_idx, const float* __restrict__ tk_w,
    const int* __restrict__ base, int* cursors, int* token_id, float* roww,
    int* slot_of)
{
    int t = blockIdx.x * 256 + threadIdx.x;
#pragma unroll
    for (int k = 0; k < 2; k++) {
        int e = tk_idx[2 * t + k];
        int pos = atomicAdd(&cursors[e], 1);
        int slot = base[e] + pos;
        token_id[slot] = t;
        roww[slot] = tk_w[2 * t + k];
        slot_of[2 * t + k] = slot;
    }
}

// ---------------- pack: xg[slot] = xb[token_id[slot]] (0 for pad) ----------------
__global__ __launch_bounds__(256) void pack_x_kernel(
    const __bf16* __restrict__ xb, const int* __restrict__ token_id,
    __bf16* __restrict__ xg)
{
    int tid = threadIdx.x;
    int slot = blockIdx.x * 2 + (tid >> 7);
    int off = (tid & 127) * 8;
    int tok = token_id[slot];
    uint4 v = {0u, 0u, 0u, 0u};
    if (tok >= 0) v = *(const uint4*)(xb + (size_t)tok * EMB + off);
    *(uint4*)(xg + (size_t)slot * EMB + off) = v;
}

// ---------------- combine (y in bf16) ----------------
__global__ __launch_bounds__(256) void combine_kernel(
    const __bf16* __restrict__ y0, const __bf16* __restrict__ y1, int nsplit,
    const int* __restrict__ slot_of,
    const int* __restrict__ tk_idx, const float* __restrict__ tk_w,
    const float* __restrict__ b2, float* __restrict__ out)
{
    int t = blockIdx.x;
    int dq = threadIdx.x * 4;
    int s0 = slot_of[2 * t], s1 = slot_of[2 * t + 1];
    int e0 = tk_idx[2 * t], e1 = tk_idx[2 * t + 1];
    float w0 = tk_w[2 * t], w1 = tk_w[2 * t + 1];
    bf16x4 va = *(const bf16x4*)(y0 + (size_t)s0 * EMB + dq);
    bf16x4 vb = *(const bf16x4*)(y0 + (size_t)s1 * EMB + dq);
    f32x4 ya, yb;
#pragma unroll
    for (int q = 0; q < 4; q++) { ya[q] = (float)va[q]; yb[q] = (float)vb[q]; }
    if (nsplit == 2) {
        bf16x4 za = *(const bf16x4*)(y1 + (size_t)s0 * EMB + dq);
        bf16x4 zb = *(const bf16x4*)(y1 + (size_t)s1 * EMB + dq);
#pragma unroll
        for (int q = 0; q < 4; q++) { ya[q] += (float)za[q]; yb[q] += (float)zb[q]; }
    }
    f32x4 ba = *(const f32x4*)(b2 + (size_t)e0 * EMB + dq);
    f32x4 bb = *(const f32x4*)(b2 + (size_t)e1 * EMB + dq);
    f32x4 r;
#pragma unroll
    for (int q = 0; q < 4; q++) r[q] = w0 * (ya[q] + ba[q]) + w1 * (yb[q] + bb[q]);
    *(f32x4*)(out + (size_t)t * EMB + dq) = r;
}

// merged transpose: flat grid; f>>13 selects W1 (0) / W2 (1)
__global__ __launch_bounds__(256) void transpose_cvt2_kernel(
    const float* __restrict__ W1, __bf16* __restrict__ W1T,
    const float* __restrict__ W2, __bf16* __restrict__ W2T)
{
    int f = blockIdx.x;
    int which = f >> 13; f &= 8191;
    int e = f >> 10; f &= 1023;
    int R, C, bx, by;
    const float* src; __bf16* dst;
    if (which == 0) { R = EMB; C = FF;  bx = f & 15; by = f >> 4; src = W1; dst = W1T; }
    else            { R = FF;  C = EMB; bx = f & 63; by = f >> 6; src = W2; dst = W2T; }
    src += (size_t)e * R * C;
    dst += (size_t)e * R * C;
    __shared__ __bf16 Ls[64 * 72];
    int t = threadIdx.x;
    int r0 = bx * 64, c0 = by * 64;
    int ri = t >> 4, cj = (t & 15) * 4;
#pragma unroll
    for (int p = 0; p < 4; p++) {
        int r = ri + p * 16;
        f32x4 v = *(const f32x4*)(src + (size_t)(r0 + r) * C + c0 + cj);
#pragma unroll
        for (int q = 0; q < 4; q++) Ls[(cj + q) * 72 + r] = (__bf16)v[q];
    }
    __syncthreads();
    int c = t >> 2, rq = (t & 3) * 16;
    bf16x8 a = *(bf16x8*)&Ls[c * 72 + rq];
    bf16x8 b = *(bf16x8*)&Ls[c * 72 + rq + 8];
    *(bf16x8*)(dst + (size_t)(c0 + c) * R + r0 + rq) = a;
    *(bf16x8*)(dst + (size_t)(c0 + c) * R + r0 + rq + 8) = b;
}

// ============================================================================
// gemm1 (r15 green): BM=128, BN=128, BK=32, 256 thr (4 waves 2x2, wave tile
// 64x64, acc[4][4]). 3 LDS bufs x 16KB = 48KB -> 3 blocks/CU, 3 independent
// barrier domains. L2-blocked grid: nbg outer (4 groups of 8), sti middle,
// nbi inner. Pipeline: counted vmcnt(4), XOR chunk swizzle, 0 conflicts.
// ============================================================================

template <bool PACKED>
__global__ __launch_bounds__(256, 3) void gemm1_8p(
    const __bf16* __restrict__ xsrc, const __bf16* __restrict__ W1T,
    const float* __restrict__ b1,
    const int* __restrict__ token_id, const int* __restrict__ tile_e,
    const int* __restrict__ tile_rb, const int* __restrict__ ntiles,
    __bf16* __restrict__ h)
{
    extern __shared__ __bf16 lds[];   // 3 bufs x 8192 elems
    int flat = blockIdx.x;
    int c8 = flat & 7, r = flat >> 3;
    int nbg = r / 144;
    int rem = r - nbg * 144;
    int sti = rem >> 3;
    int nb  = (nbg << 3) | (rem & 7);
    int st = c8 * 18 + sti;
    if (st >= *ntiles * 2) return;
    int e = tile_e[st >> 1];
    int rb = tile_rb[st >> 1] + (st & 1) * 128;
    int n0 = nb * 128;

    int tid = threadIdx.x, lane = tid & 63, wid = tid >> 6;
    int wr = wid >> 1, wc = wid & 1;
    int cl = lane & 15, cq = lane >> 4;

    int srow1 = ((tid >> 6) << 4) | ((tid & 63) >> 2);
    int schunk = (tid & 3) ^ ((tid >> 3) & 3);
    const __bf16* ag[2];
#pragma unroll
    for (int hm = 0; hm < 2; hm++) {
        int row = srow1 + hm * 64;
        if (PACKED) {
            ag[hm] = xsrc + (size_t)(rb + row) * EMB + schunk * 8;
        } else {
            int tok = token_id[rb + row];
            if (tok < 0) tok = 0;
            ag[hm] = xsrc + (size_t)tok * EMB + schunk * 8;
        }
    }
    const __bf16* bg[2];
#pragma unroll
    for (int hn = 0; hn < 2; hn++)
        bg[hn] = W1T + ((size_t)e * FF + (size_t)(n0 + srow1 + hn * 64)) * EMB + schunk * 8;

    int sdA0 = wid * 512, sdA1 = 2048 + wid * 512;
    int sdB0 = 4096 + wid * 512, sdB1 = 6144 + wid * 512;

    uint32_t lb = (uint32_t)(uintptr_t)(__attribute__((address_space(3))) __bf16*)lds;
    int xoffe = (cq ^ ((cl >> 1) & 3)) * 8;
    uint32_t ab0 = lb + 2u * (uint32_t)(wr * 2048 + cl * 32 + xoffe);
    uint32_t bb0 = lb + 2u * (uint32_t)(4096 + wc * 2048 + cl * 32 + xoffe);

    f32x4 acc[4][4];
#pragma unroll
    for (int i = 0; i < 4; i++)
#pragma unroll
        for (int j = 0; j < 4; j++) acc[i][j] = fzero();

    const int NT = EMB / 32;
#pragma unroll
    for (int t0 = 0; t0 < 2; t0++) {
        __bf16* bp = lds + t0 * 8192;
        int k0 = t0 * 32;
        gl16(ag[0] + k0, bp + sdA0);
        gl16(ag[1] + k0, bp + sdA1);
        gl16(bg[0] + k0, bp + sdB0);
        gl16(bg[1] + k0, bp + sdB1);
    }
    asm volatile("s_waitcnt vmcnt(4)" ::: "memory");
    __builtin_amdgcn_s_barrier();

    int cb = 0;
#pragma unroll 1
    for (int t = 0; t < NT; t++) {
        uint32_t cboff = (uint32_t)cb * 16384u;
        uint32_t aaddr = ab0 + cboff, baddr = bb0 + cboff;
        bf16x8 b[4], a[4];
        DSR(b[0], baddr, 0);    DSR(b[1], baddr, 1024);
        DSR(b[2], baddr, 2048); DSR(b[3], baddr, 3072);
        DSR(a[0], aaddr, 0);    DSR(a[1], aaddr, 1024);
        DSR(a[2], aaddr, 2048); DSR(a[3], aaddr, 3072);

        int kt = t + 2;
        if (kt < NT) {
            int sb = cb + 2; if (sb >= 3) sb -= 3;
            __bf16* sp = lds + sb * 8192;
            int ko = kt * 32;
            gl16(ag[0] + ko, sp + sdA0);
            gl16(ag[1] + ko, sp + sdA1);
            gl16(bg[0] + ko, sp + sdB0);
            gl16(bg[1] + ko, sp + sdB1);
        }

        asm volatile("s_waitcnt lgkmcnt(0)" ::: "memory");
        __builtin_amdgcn_sched_barrier(0);
        __builtin_amdgcn_s_setprio(1);
#pragma unroll
        for (int mi = 0; mi < 4; mi++)
#pragma unroll
            for (int ni = 0; ni < 4; ni++)
                acc[mi][ni] = __builtin_amdgcn_mfma_f32_16x16x32_bf16(a[mi], b[ni], acc[mi][ni], 0, 0, 0);
        __builtin_amdgcn_s_setprio(0);

        if (t < NT - 2)       { asm volatile("s_waitcnt vmcnt(4)" ::: "memory"); }
        else if (t == NT - 2) { asm volatile("s_waitcnt vmcnt(0)" ::: "memory"); }
        if (t < NT - 1) __builtin_amdgcn_s_barrier();
        cb = cb + 1; if (cb >= 3) cb = 0;
    }

    const float* b1g = b1 + (size_t)e * FF + n0;
#pragma unroll
    for (int mi = 0; mi < 4; mi++) {
#pragma unroll
        for (int ni = 0; ni < 4; ni++) {
            int col = wc * 64 + ni * 16 + cl;
            float bias = b1g[col];
#pragma unroll
            for (int j = 0; j < 4; j++) {
                int row = wr * 64 + mi * 16 + cq * 4 + j;
                float v = acc[mi][ni][j] + bias;
                h[(size_t)(rb + row) * FF + n0 + col] = (__bf16)gelu_f(v);
            }
        }
    }
}

// ============================================================================
// gemm2 (NEW: gemm1's proven structure ported): BM=128, BN=128, BK=32,
// 256 thr, 3 LDS bufs x 16KB -> 3 blocks/CU. L2-blocked grid per XCD:
// z (K-split) outer, nbg (2 groups of 4 n-panels) outer, sti middle, nbi
// inner -> inner working set 4 B panels (512KB ea @nsplit=2) + A subtile
// (512KB) = 2.5MB < 4MB L2. Same verified pipeline.
// ============================================================================
__global__ __launch_bounds__(256, 3) void gemm2_128(
    const __bf16* __restrict__ h, const __bf16* __restrict__ W2T,
    const int* __restrict__ tile_e, const int* __restrict__ tile_rb,
    const int* __restrict__ ntiles,
    __bf16* __restrict__ y0, __bf16* __restrict__ y1, int nsplit)
{
    extern __shared__ __bf16 lds[];
    int flat = blockIdx.x;
    int c8 = flat & 7, r = flat >> 3;
    int z = r / 144;
    int rem = r - z * 144;
    int nbg = rem / 72;
    int rem2 = rem - nbg * 72;
    int sti = rem2 >> 2, nbi = rem2 & 3;
    int nb = (nbg << 2) | nbi;
    int st = c8 * 18 + sti;
    if (st >= *ntiles * 2) return;
    int e = tile_e[st >> 1];
    int rb = tile_rb[st >> 1] + (st & 1) * 128;
    int n0 = nb * 128;
    int KC = FF / nsplit;
    int koff = z * KC;
    __bf16* y = z ? y1 : y0;

    int tid = threadIdx.x, lane = tid & 63, wid = tid >> 6;
    int wr = wid >> 1, wc = wid & 1;
    int cl = lane & 15, cq = lane >> 4;

    int srow1 = ((tid >> 6) << 4) | ((tid & 63) >> 2);
    int schunk = (tid & 3) ^ ((tid >> 3) & 3);
    const __bf16* ag[2];
#pragma unroll
    for (int hm = 0; hm < 2; hm++)
        ag[hm] = h + (size_t)(rb + srow1 + hm * 64) * FF + koff + schunk * 8;
    const __bf16* bg[2];
#pragma unroll
    for (int hn = 0; hn < 2; hn++)
        bg[hn] = W2T + ((size_t)e * EMB + (size_t)(n0 + srow1 + hn * 64)) * FF + koff + schunk * 8;

    int sdA0 = wid * 512, sdA1 = 2048 + wid * 512;
    int sdB0 = 4096 + wid * 512, sdB1 = 6144 + wid * 512;

    uint32_t lb = (uint32_t)(uintptr_t)(__attribute__((address_space(3))) __bf16*)lds;
    int xoffe = (cq ^ ((cl >> 1) & 3)) * 8;
    uint32_t ab0 = lb + 2u * (uint32_t)(wr * 2048 + cl * 32 + xoffe);
    uint32_t bb0 = lb + 2u * (uint32_t)(4096 + wc * 2048 + cl * 32 + xoffe);

    f32x4 acc[4][4];
#pragma unroll
    for (int i = 0; i < 4; i++)
#pragma unroll
        for (int j = 0; j < 4; j++) acc[i][j] = fzero();

    const int NT = KC / 32;
#pragma unroll
    for (int t0 = 0; t0 < 2; t0++) {
        __bf16* bp = lds + t0 * 8192;
        int k0 = t0 * 32;
        gl16(ag[0] + k0, bp + sdA0);
        gl16(ag[1] + k0, bp + sdA1);
        gl16(bg[0] + k0, bp + sdB0);
        gl16(bg[1] + k0, bp + sdB1);
    }
    asm volatile("s_waitcnt vmcnt(4)" ::: "memory");
    __builtin_amdgcn_s_barrier();

    int cb = 0;
#pragma unroll 1
    for (int t = 0; t < NT; t++) {
        uint32_t cboff = (uint32_t)cb * 16384u;
        uint32_t aaddr = ab0 + cboff, baddr = bb0 + cboff;
        bf16x8 b[4], a[4];
        DSR(b[0], baddr, 0);    DSR(b[1], baddr, 1024);
        DSR(b[2], baddr, 2048); DSR(b[3], baddr, 3072);
        DSR(a[0], aaddr, 0);    DSR(a[1], aaddr, 1024);
        DSR(a[2], aaddr, 2048); DSR(a[3], aaddr, 3072);

        int kt = t + 2;
        if (kt < NT) {
            int sb = cb + 2; if (sb >= 3) sb -= 3;
            __bf16* sp = lds + sb * 8192;
            int ko = kt * 32;
            gl16(ag[0] + ko, sp + sdA0);
            gl16(ag[1] + ko, sp + sdA1);
            gl16(bg[0] + ko, sp + sdB0);
            gl16(bg[1] + ko, sp + sdB1);
        }

        asm volatile("s_waitcnt lgkmcnt(0)" ::: "memory");
        __builtin_amdgcn_sched_barrier(0);
        __builtin_amdgcn_s_setprio(1);
#pragma unroll
        for (int mi = 0; mi < 4; mi++)
#pragma unroll
            for (int ni = 0; ni < 4; ni++)
                acc[mi][ni] = __builtin_amdgcn_mfma_f32_16x16x32_bf16(a[mi], b[ni], acc[mi][ni], 0, 0, 0);
        __builtin_amdgcn_s_setprio(0);

        if (t < NT - 2)       { asm volatile("s_waitcnt vmcnt(4)" ::: "memory"); }
        else if (t == NT - 2) { asm volatile("s_waitcnt vmcnt(0)" ::: "memory"); }
        if (t < NT - 1) __builtin_amdgcn_s_barrier();
        cb = cb + 1; if (cb >= 3) cb = 0;
    }

#pragma unroll
    for (int mi = 0; mi < 4; mi++) {
#pragma unroll
        for (int ni = 0; ni < 4; ni++) {
            int col = wc * 64 + ni * 16 + cl;
#pragma unroll
            for (int j = 0; j < 4; j++) {
                int row = wr * 64 + mi * 16 + cq * 4 + j;
                y[(size_t)(rb + row) * EMB + n0 + col] = (__bf16)acc[mi][ni][j];
            }
        }
    }
}

extern "C" void kernel_launch(void* const* d_in, const int* in_sizes, int n_in,
                              void* d_out, int out_size, void* d_ws, size_t ws_size,
                              hipStream_t stream)
{
    const float* x   = (const float*)d_in[0];
    const float* gW  = (const float*)d_in[1];
    const float* gb  = (const float*)d_in[2];
    const float* W1  = (const float*)d_in[3];
    const float* b1  = (const float*)d_in[4];
    const float* W2  = (const float*)d_in[5];
    const float* b2  = (const float*)d_in[6];
    float* out = (float*)d_out;

    char* ws = (char*)d_ws;
    int*   counts  = (int*)(ws + WS_COUNTS);
    int*   cursors = (int*)(ws + WS_CURSORS);
    float* ssum    = (float*)(ws + WS_SSUM);
    int*   ntiles  = (int*)(ws + WS_NTILES);
    int*   base    = (int*)(ws + WS_BASE);
    int*   tile_e  = (int*)(ws + WS_TILE_E);
    int*   tile_rb = (int*)(ws + WS_TILE_RB);
    int*   tk_idx  = (int*)(ws + WS_TKIDX);
    float* tk_w    = (float*)(ws + WS_TKW);
    int*   slot_of = (int*)(ws + WS_SLOT);
    int*   token_id= (int*)(ws + WS_TOKID);
    float* roww    = (float*)(ws + WS_ROWW);

    __bf16* W1T  = (__bf16*)(ws + WS_BIG2);
    __bf16* xb   = (__bf16*)(ws + WS_BIG2 + SZ_W1T);
    __bf16* W2T  = (__bf16*)(ws + WS_BIG2 + SZ_W1T + SZ_XB);
    __bf16* hbuf = (__bf16*)(ws + WS_BIG2 + SZ_W1T + SZ_XB + SZ_W2T);
    size_t fixedend = WS_BIG2 + SZ_W1T + SZ_XB + SZ_W2T;

    __bf16* y0 = (__bf16*)(ws + WS_BIG2);            // aliases W1T+xb (dead after gemm1)
    __bf16* xg = (__bf16*)(ws + fixedend + SZ_H);
    bool packed = (ws_size >= fixedend + SZ_H + SZ_XG);
    __bf16* y1 = (__bf16*)(ws + fixedend + SZ_H + (packed ? SZ_XG : 0));
    int nsplit = (ws_size >= fixedend + SZ_H + (packed ? SZ_XG : 0) + SZ_Y2) ? 2 : 1;

    hipFuncSetAttribute((const void*)gemm1_8p<true>,  hipFuncAttributeMaxDynamicSharedMemorySize, 49152);
    hipFuncSetAttribute((const void*)gemm1_8p<false>, hipFuncAttributeMaxDynamicSharedMemorySize, 49152);
    hipFuncSetAttribute((const void*)gemm2_128, hipFuncAttributeMaxDynamicSharedMemorySize, 49152);

    hipMemsetAsync(ws + WS_COUNTS, 0, 2080, stream);
    hipMemsetAsync(ws + WS_TOKID, 0xFF, (size_t)MAXROWS * 4, stream);

    transpose_cvt2_kernel<<<16384, 256, 0, stream>>>(W1, W1T, W2, W2T);

    gate_kernel<<<TTOK / 4, 256, 0, stream>>>(x, gW, gb, counts, ssum, tk_idx, tk_w, xb);
    route_build_kernel<<<1, 64, 0, stream>>>(counts, ssum, ntiles, base, tile_e, tile_rb,
                                             out + (size_t)TTOK * EMB);
    scatter_kernel<<<TTOK / 256, 256, 0, stream>>>(tk_idx, tk_w, base, cursors, token_id, roww, slot_of);

    if (packed) {
        pack_x_kernel<<<MAXROWS / 2, 256, 0, stream>>>(xb, token_id, xg);
        gemm1_8p<true><<<8 * 18 * 32, 256, 49152, stream>>>(
            xg, W1T, b1, token_id, tile_e, tile_rb, ntiles, hbuf);
    } else {
        gemm1_8p<false><<<8 * 18 * 32, 256, 49152, stream>>>(
            xb, W1T, b1, token_id, tile_e, tile_rb, ntiles, hbuf);
    }
    gemm2_128<<<8 * 144 * nsplit, 256, 49152, stream>>>(
        hbuf, W2T, tile_e, tile_rb, ntiles, y0, y1, nsplit);
    combine_kernel<<<TTOK, 256, 0, stream>>>(y0, y1, nsplit, slot_of, tk_idx, tk_w, b2, out);
}

// Round 17
// 621.089 us; speedup vs baseline: 1.1068x; 1.0936x over previous
//
#include <hip/hip_runtime.h>
#include <math.h>

#define EMB 1024
#define FF  4096
#define NE  8
#define TTOK 8192

typedef __attribute__((ext_vector_type(4))) float  f32x4;
typedef __attribute__((ext_vector_type(8))) __bf16 bf16x8;
typedef __attribute__((ext_vector_type(4))) __bf16 bf16x4;

#define MAXROWS  18432   // 16384 assignments + 8*256 padding

// ---- ws layout (bytes) ----
#define WS_COUNTS  0        // int[256]
#define WS_CURSORS 1024     // int[256] (sharded)
#define WS_SSUM    2048     // float[256]
#define WS_CELLB   3072     // int[256] per-cell slot bases
#define WS_NTILES  4096
#define WS_BASE    4100
#define WS_TILE_E  4160     // int[160]
#define WS_TILE_RB 4800     // int[160]
#define WS_TKIDX   8192     // int[2*TTOK]
#define WS_TKW     73728    // float[2*TTOK]
#define WS_SLOT    139264   // int[2*TTOK]
#define WS_TOKID   204800   // int[MAXROWS]
#define WS_ROWW    278528   // float[MAXROWS]
#define WS_BIG2    352256   // [W1T | xb | W2T | h | xg | (y1)]

#define SZ_W1T ((size_t)NE * EMB * FF * 2)   // 64 MB
#define SZ_W2T ((size_t)NE * EMB * FF * 2)   // 64 MB
#define SZ_XB  ((size_t)TTOK * EMB * 2)      // 16 MB
#define SZ_H   ((size_t)MAXROWS * FF * 2)    // 144 MB
#define SZ_XG  ((size_t)MAXROWS * EMB * 2)   // 36 MB
#define SZ_Y2  ((size_t)MAXROWS * EMB * 2)   // 36 MB (bf16 y)

__device__ inline f32x4 fzero() { f32x4 v = {0.f, 0.f, 0.f, 0.f}; return v; }

__device__ __forceinline__ void gl16(const void* g, void* l) {
    __builtin_amdgcn_global_load_lds(
        (const __attribute__((address_space(1))) void*)g,
        (__attribute__((address_space(3))) void*)l, 16, 0, 0);
}

// compiler-invisible LDS read: ds_read_b128 at 32-bit LDS byte addr + literal imm
#define DSR(dst, addr, off) \
    asm volatile("ds_read_b128 %0, %1 offset:" #off : "=v"(dst) : "v"(addr))

// fast erf-gelu (A&S 7.1.25, |erf err| <= 5e-4; bf16 h quantization dominates)
__device__ __forceinline__ float gelu_f(float v) {
    float u = fabsf(v) * 0.70710678118654752f;
    float p = 1.0f + u * (0.278393f + u * (0.230389f + u * (0.000972f + u * 0.078108f)));
    p = p * p; p = p * p;
    float er = 1.0f - 1.0f / p;
    float s = (v >= 0.0f) ? er : -er;
    return 0.5f * v * (1.0f + s);
}

// ---------------- gating (also emits xb = bf16(x)) ----------------
__global__ __launch_bounds__(256) void gate_kernel(
    const float* __restrict__ x, const float* __restrict__ gW, const float* __restrict__ gb,
    int* counts, float* ssum, int* tk_idx, float* tk_w, __bf16* __restrict__ xb)
{
    int wave = threadIdx.x >> 6;
    int lane = threadIdx.x & 63;
    int t = blockIdx.x * 4 + wave;

    float acc[NE];
#pragma unroll
    for (int e = 0; e < NE; e++) acc[e] = 0.f;

    const float* xr = x + (size_t)t * EMB;
    __bf16* xbr = xb + (size_t)t * EMB;
#pragma unroll
    for (int i = 0; i < 4; i++) {
        int d0 = i * 256 + lane * 4;
        f32x4 xv = *(const f32x4*)(xr + d0);
        bf16x4 cv;
#pragma unroll
        for (int q = 0; q < 4; q++) cv[q] = (__bf16)xv[q];
        *(bf16x4*)(xbr + d0) = cv;
#pragma unroll
        for (int j = 0; j < 4; j++) {
            const float* wrow = gW + (size_t)(d0 + j) * NE;
            float xs = xv[j];
#pragma unroll
            for (int e = 0; e < NE; e++) acc[e] += xs * wrow[e];
        }
    }
#pragma unroll
    for (int e = 0; e < NE; e++) {
#pragma unroll
        for (int off = 32; off; off >>= 1) acc[e] += __shfl_xor(acc[e], off, 64);
    }
    if (lane == 0) {
        float sc[NE];
        float m = -1e30f;
        for (int e = 0; e < NE; e++) { sc[e] = acc[e] + gb[e]; m = fmaxf(m, sc[e]); }
        float sum = 0.f;
        for (int e = 0; e < NE; e++) { sc[e] = expf(sc[e] - m); sum += sc[e]; }
        float inv = 1.f / sum;
        for (int e = 0; e < NE; e++) sc[e] *= inv;
        int i0 = 0; float s0 = sc[0];
        for (int e = 1; e < NE; e++) if (sc[e] > s0) { s0 = sc[e]; i0 = e; }
        int i1 = -1; float s1 = -1e30f;
        for (int e = 0; e < NE; e++) if (e != i0 && sc[e] > s1) { s1 = sc[e]; i1 = e; }
        float rn = 1.f / (s0 + s1);
        tk_idx[2 * t]     = i0;  tk_idx[2 * t + 1] = i1;
        tk_w[2 * t]       = s0 * rn;  tk_w[2 * t + 1] = s1 * rn;
        int slot = blockIdx.x & 31;
        atomicAdd(&counts[i0 * 32 + slot], 1);
        atomicAdd(&counts[i1 * 32 + slot], 1);
        for (int e = 0; e < NE; e++) atomicAdd(&ssum[e * 32 + slot], sc[e]);
    }
}

// ---------------- routing tables + per-cell bases + aux (parallel) ----------------
// 1 block x 256 threads; thread tid = e*32+s handles cell (e,s).
__global__ __launch_bounds__(256) void route_build_kernel(
    const int* counts, const float* ssum,
    int* ntiles, int* base, int* tile_e, int* tile_rb, int* cellbase,
    float* out_aux)
{
    int tid = threadIdx.x;
    int e = tid >> 5, s = tid & 31;
    int c = counts[tid];
    float ss = ssum[tid];

    // inclusive scan of c within the 32-lane cell group
    int inc = c;
#pragma unroll
    for (int d = 1; d < 32; d <<= 1) {
        int t2 = __shfl_up(inc, d, 32);
        if (s >= d) inc += t2;
    }
    float sr = ss;
#pragma unroll
    for (int d = 1; d < 32; d <<= 1) {
        float t2 = __shfl_up(sr, d, 32);
        if (s >= d) sr += t2;
    }

    __shared__ int ctot[NE];
    __shared__ float sstot[NE];
    __shared__ int ebase[NE];
    if (s == 31) { ctot[e] = inc; sstot[e] = sr; }
    __syncthreads();

    if (tid == 0) {
        int total = 0, tiles = 0;
        float aux = 0.f;
        for (int ee = 0; ee < NE; ee++) {
            ebase[ee] = total;
            int nt = (ctot[ee] + 255) >> 8;
            for (int i = 0; i < nt; i++) { tile_e[tiles] = ee; tile_rb[tiles] = total + (i << 8); tiles++; }
            total += nt << 8;
            aux += ((float)ctot[ee] / (float)(TTOK * 2)) * (sstot[ee] / (float)TTOK);
        }
        *ntiles = tiles;
        *out_aux = aux * (float)NE;
    }
    __syncthreads();
    cellbase[tid] = ebase[e] + (inc - c);   // exclusive prefix within expert
    if (s == 0) base[e] = ebase[e];
}

// ---------------- scatter: sharded cursors (cell = e*32 + (t>>2)&31) ----------------
__global__ __launch_bounds__(256) void scatter_kernel(
    const int* __restrict__ tk_idx, const float* __restrict__ tk_w,
    const int* __restrict__ cellbase, int* cursors, int* token_id, float* roww,
    int* slot_of)
{
    int t = blockIdx.x * 256 + threadIdx.x;
    int shard = (t >> 2) & 31;   // same sharding the gate used for counts
#pragma unroll
    for (int k = 0; k < 2; k++) {
        int e = tk_idx[2 * t + k];
        int cell = e * 32 + shard;
        int pos = atomicAdd(&cursors[cell], 1);
        int slot = cellbase[cell] + pos;
        token_id[slot] = t;
        roww[slot] = tk_w[2 * t + k];
        slot_of[2 * t + k] = slot;
    }
}

// ---------------- pack: xg[slot] = xb[token_id[slot]] (0 for pad) ----------------
__global__ __launch_bounds__(256) void pack_x_kernel(
    const __bf16* __restrict__ xb, const int* __restrict__ token_id,
    __bf16* __restrict__ xg)
{
    int tid = threadIdx.x;
    int slot = blockIdx.x * 2 + (tid >> 7);
    int off = (tid & 127) * 8;
    int tok = token_id[slot];
    uint4 v = {0u, 0u, 0u, 0u};
    if (tok >= 0) v = *(const uint4*)(xb + (size_t)tok * EMB + off);
    *(uint4*)(xg + (size_t)slot * EMB + off) = v;
}

// ---------------- combine (y in bf16) ----------------
__global__ __launch_bounds__(256) void combine_kernel(
    const __bf16* __restrict__ y0, const __bf16* __restrict__ y1, int nsplit,
    const int* __restrict__ slot_of,
    const int* __restrict__ tk_idx, const float* __restrict__ tk_w,
    const float* __restrict__ b2, float* __restrict__ out)
{
    int t = blockIdx.x;
    int dq = threadIdx.x * 4;
    int s0 = slot_of[2 * t], s1 = slot_of[2 * t + 1];
    int e0 = tk_idx[2 * t], e1 = tk_idx[2 * t + 1];
    float w0 = tk_w[2 * t], w1 = tk_w[2 * t + 1];
    bf16x4 va = *(const bf16x4*)(y0 + (size_t)s0 * EMB + dq);
    bf16x4 vb = *(const bf16x4*)(y0 + (size_t)s1 * EMB + dq);
    f32x4 ya, yb;
#pragma unroll
    for (int q = 0; q < 4; q++) { ya[q] = (float)va[q]; yb[q] = (float)vb[q]; }
    if (nsplit == 2) {
        bf16x4 za = *(const bf16x4*)(y1 + (size_t)s0 * EMB + dq);
        bf16x4 zb = *(const bf16x4*)(y1 + (size_t)s1 * EMB + dq);
#pragma unroll
        for (int q = 0; q < 4; q++) { ya[q] += (float)za[q]; yb[q] += (float)zb[q]; }
    }
    f32x4 ba = *(const f32x4*)(b2 + (size_t)e0 * EMB + dq);
    f32x4 bb = *(const f32x4*)(b2 + (size_t)e1 * EMB + dq);
    f32x4 r;
#pragma unroll
    for (int q = 0; q < 4; q++) r[q] = w0 * (ya[q] + ba[q]) + w1 * (yb[q] + bb[q]);
    *(f32x4*)(out + (size_t)t * EMB + dq) = r;
}

// merged transpose: flat grid; f>>13 selects W1 (0) / W2 (1)
__global__ __launch_bounds__(256) void transpose_cvt2_kernel(
    const float* __restrict__ W1, __bf16* __restrict__ W1T,
    const float* __restrict__ W2, __bf16* __restrict__ W2T)
{
    int f = blockIdx.x;
    int which = f >> 13; f &= 8191;
    int e = f >> 10; f &= 1023;
    int R, C, bx, by;
    const float* src; __bf16* dst;
    if (which == 0) { R = EMB; C = FF;  bx = f & 15; by = f >> 4; src = W1; dst = W1T; }
    else            { R = FF;  C = EMB; bx = f & 63; by = f >> 6; src = W2; dst = W2T; }
    src += (size_t)e * R * C;
    dst += (size_t)e * R * C;
    __shared__ __bf16 Ls[64 * 72];
    int t = threadIdx.x;
    int r0 = bx * 64, c0 = by * 64;
    int ri = t >> 4, cj = (t & 15) * 4;
#pragma unroll
    for (int p = 0; p < 4; p++) {
        int r = ri + p * 16;
        f32x4 v = *(const f32x4*)(src + (size_t)(r0 + r) * C + c0 + cj);
#pragma unroll
        for (int q = 0; q < 4; q++) Ls[(cj + q) * 72 + r] = (__bf16)v[q];
    }
    __syncthreads();
    int c = t >> 2, rq = (t & 3) * 16;
    bf16x8 a = *(bf16x8*)&Ls[c * 72 + rq];
    bf16x8 b = *(bf16x8*)&Ls[c * 72 + rq + 8];
    *(bf16x8*)(dst + (size_t)(c0 + c) * R + r0 + rq) = a;
    *(bf16x8*)(dst + (size_t)(c0 + c) * R + r0 + rq + 8) = b;
}

// ============================================================================
// gemm1 (r15/16 green): BM=128, BN=128, BK=32, 256 thr (4 waves 2x2, wave
// tile 64x64, acc[4][4]). 3 LDS bufs x 16KB = 48KB -> 3 blocks/CU, 3
// independent barrier domains. L2-blocked grid: nbg outer (4 groups of 8),
// sti middle, nbi inner. Counted vmcnt(4), XOR chunk swizzle, 0 conflicts.
// ============================================================================

template <bool PACKED>
__global__ __launch_bounds__(256, 3) void gemm1_8p(
    const __bf16* __restrict__ xsrc, const __bf16* __restrict__ W1T,
    const float* __restrict__ b1,
    const int* __restrict__ token_id, const int* __restrict__ tile_e,
    const int* __restrict__ tile_rb, const int* __restrict__ ntiles,
    __bf16* __restrict__ h)
{
    extern __shared__ __bf16 lds[];   // 3 bufs x 8192 elems
    int flat = blockIdx.x;
    int c8 = flat & 7, r = flat >> 3;
    int nbg = r / 144;
    int rem = r - nbg * 144;
    int sti = rem >> 3;
    int nb  = (nbg << 3) | (rem & 7);
    int st = c8 * 18 + sti;
    if (st >= *ntiles * 2) return;
    int e = tile_e[st >> 1];
    int rb = tile_rb[st >> 1] + (st & 1) * 128;
    int n0 = nb * 128;

    int tid = threadIdx.x, lane = tid & 63, wid = tid >> 6;
    int wr = wid >> 1, wc = wid & 1;
    int cl = lane & 15, cq = lane >> 4;

    int srow1 = ((tid >> 6) << 4) | ((tid & 63) >> 2);
    int schunk = (tid & 3) ^ ((tid >> 3) & 3);
    const __bf16* ag[2];
#pragma unroll
    for (int hm = 0; hm < 2; hm++) {
        int row = srow1 + hm * 64;
        if (PACKED) {
            ag[hm] = xsrc + (size_t)(rb + row) * EMB + schunk * 8;
        } else {
            int tok = token_id[rb + row];
            if (tok < 0) tok = 0;
            ag[hm] = xsrc + (size_t)tok * EMB + schunk * 8;
        }
    }
    const __bf16* bg[2];
#pragma unroll
    for (int hn = 0; hn < 2; hn++)
        bg[hn] = W1T + ((size_t)e * FF + (size_t)(n0 + srow1 + hn * 64)) * EMB + schunk * 8;

    int sdA0 = wid * 512, sdA1 = 2048 + wid * 512;
    int sdB0 = 4096 + wid * 512, sdB1 = 6144 + wid * 512;

    uint32_t lb = (uint32_t)(uintptr_t)(__attribute__((address_space(3))) __bf16*)lds;
    int xoffe = (cq ^ ((cl >> 1) & 3)) * 8;
    uint32_t ab0 = lb + 2u * (uint32_t)(wr * 2048 + cl * 32 + xoffe);
    uint32_t bb0 = lb + 2u * (uint32_t)(4096 + wc * 2048 + cl * 32 + xoffe);

    f32x4 acc[4][4];
#pragma unroll
    for (int i = 0; i < 4; i++)
#pragma unroll
        for (int j = 0; j < 4; j++) acc[i][j] = fzero();

    const int NT = EMB / 32;
#pragma unroll
    for (int t0 = 0; t0 < 2; t0++) {
        __bf16* bp = lds + t0 * 8192;
        int k0 = t0 * 32;
        gl16(ag[0] + k0, bp + sdA0);
        gl16(ag[1] + k0, bp + sdA1);
        gl16(bg[0] + k0, bp + sdB0);
        gl16(bg[1] + k0, bp + sdB1);
    }
    asm volatile("s_waitcnt vmcnt(4)" ::: "memory");
    __builtin_amdgcn_s_barrier();

    int cb = 0;
#pragma unroll 1
    for (int t = 0; t < NT; t++) {
        uint32_t cboff = (uint32_t)cb * 16384u;
        uint32_t aaddr = ab0 + cboff, baddr = bb0 + cboff;
        bf16x8 b[4], a[4];
        DSR(b[0], baddr, 0);    DSR(b[1], baddr, 1024);
        DSR(b[2], baddr, 2048); DSR(b[3], baddr, 3072);
        DSR(a[0], aaddr, 0);    DSR(a[1], aaddr, 1024);
        DSR(a[2], aaddr, 2048); DSR(a[3], aaddr, 3072);

        int kt = t + 2;
        if (kt < NT) {
            int sb = cb + 2; if (sb >= 3) sb -= 3;
            __bf16* sp = lds + sb * 8192;
            int ko = kt * 32;
            gl16(ag[0] + ko, sp + sdA0);
            gl16(ag[1] + ko, sp + sdA1);
            gl16(bg[0] + ko, sp + sdB0);
            gl16(bg[1] + ko, sp + sdB1);
        }

        asm volatile("s_waitcnt lgkmcnt(0)" ::: "memory");
        __builtin_amdgcn_sched_barrier(0);
        __builtin_amdgcn_s_setprio(1);
#pragma unroll
        for (int mi = 0; mi < 4; mi++)
#pragma unroll
            for (int ni = 0; ni < 4; ni++)
                acc[mi][ni] = __builtin_amdgcn_mfma_f32_16x16x32_bf16(a[mi], b[ni], acc[mi][ni], 0, 0, 0);
        __builtin_amdgcn_s_setprio(0);

        if (t < NT - 2)       { asm volatile("s_waitcnt vmcnt(4)" ::: "memory"); }
        else if (t == NT - 2) { asm volatile("s_waitcnt vmcnt(0)" ::: "memory"); }
        if (t < NT - 1) __builtin_amdgcn_s_barrier();
        cb = cb + 1; if (cb >= 3) cb = 0;
    }

    const float* b1g = b1 + (size_t)e * FF + n0;
#pragma unroll
    for (int mi = 0; mi < 4; mi++) {
#pragma unroll
        for (int ni = 0; ni < 4; ni++) {
            int col = wc * 64 + ni * 16 + cl;
            float bias = b1g[col];
#pragma unroll
            for (int j = 0; j < 4; j++) {
                int row = wr * 64 + mi * 16 + cq * 4 + j;
                float v = acc[mi][ni][j] + bias;
                h[(size_t)(rb + row) * FF + n0 + col] = (__bf16)gelu_f(v);
            }
        }
    }
}

// ============================================================================
// gemm2 (r16 green): same structure; L2-blocked grid per XCD:
// z outer, nbg (2 groups of 4 n-panels), sti middle, nbi inner.
// ============================================================================
__global__ __launch_bounds__(256, 3) void gemm2_128(
    const __bf16* __restrict__ h, const __bf16* __restrict__ W2T,
    const int* __restrict__ tile_e, const int* __restrict__ tile_rb,
    const int* __restrict__ ntiles,
    __bf16* __restrict__ y0, __bf16* __restrict__ y1, int nsplit)
{
    extern __shared__ __bf16 lds[];
    int flat = blockIdx.x;
    int c8 = flat & 7, r = flat >> 3;
    int z = r / 144;
    int rem = r - z * 144;
    int nbg = rem / 72;
    int rem2 = rem - nbg * 72;
    int sti = rem2 >> 2, nbi = rem2 & 3;
    int nb = (nbg << 2) | nbi;
    int st = c8 * 18 + sti;
    if (st >= *ntiles * 2) return;
    int e = tile_e[st >> 1];
    int rb = tile_rb[st >> 1] + (st & 1) * 128;
    int n0 = nb * 128;
    int KC = FF / nsplit;
    int koff = z * KC;
    __bf16* y = z ? y1 : y0;

    int tid = threadIdx.x, lane = tid & 63, wid = tid >> 6;
    int wr = wid >> 1, wc = wid & 1;
    int cl = lane & 15, cq = lane >> 4;

    int srow1 = ((tid >> 6) << 4) | ((tid & 63) >> 2);
    int schunk = (tid & 3) ^ ((tid >> 3) & 3);
    const __bf16* ag[2];
#pragma unroll
    for (int hm = 0; hm < 2; hm++)
        ag[hm] = h + (size_t)(rb + srow1 + hm * 64) * FF + koff + schunk * 8;
    const __bf16* bg[2];
#pragma unroll
    for (int hn = 0; hn < 2; hn++)
        bg[hn] = W2T + ((size_t)e * EMB + (size_t)(n0 + srow1 + hn * 64)) * FF + koff + schunk * 8;

    int sdA0 = wid * 512, sdA1 = 2048 + wid * 512;
    int sdB0 = 4096 + wid * 512, sdB1 = 6144 + wid * 512;

    uint32_t lb = (uint32_t)(uintptr_t)(__attribute__((address_space(3))) __bf16*)lds;
    int xoffe = (cq ^ ((cl >> 1) & 3)) * 8;
    uint32_t ab0 = lb + 2u * (uint32_t)(wr * 2048 + cl * 32 + xoffe);
    uint32_t bb0 = lb + 2u * (uint32_t)(4096 + wc * 2048 + cl * 32 + xoffe);

    f32x4 acc[4][4];
#pragma unroll
    for (int i = 0; i < 4; i++)
#pragma unroll
        for (int j = 0; j < 4; j++) acc[i][j] = fzero();

    const int NT = KC / 32;
#pragma unroll
    for (int t0 = 0; t0 < 2; t0++) {
        __bf16* bp = lds + t0 * 8192;
        int k0 = t0 * 32;
        gl16(ag[0] + k0, bp + sdA0);
        gl16(ag[1] + k0, bp + sdA1);
        gl16(bg[0] + k0, bp + sdB0);
        gl16(bg[1] + k0, bp + sdB1);
    }
    asm volatile("s_waitcnt vmcnt(4)" ::: "memory");
    __builtin_amdgcn_s_barrier();

    int cb = 0;
#pragma unroll 1
    for (int t = 0; t < NT; t++) {
        uint32_t cboff = (uint32_t)cb * 16384u;
        uint32_t aaddr = ab0 + cboff, baddr = bb0 + cboff;
        bf16x8 b[4], a[4];
        DSR(b[0], baddr, 0);    DSR(b[1], baddr, 1024);
        DSR(b[2], baddr, 2048); DSR(b[3], baddr, 3072);
        DSR(a[0], aaddr, 0);    DSR(a[1], aaddr, 1024);
        DSR(a[2], aaddr, 2048); DSR(a[3], aaddr, 3072);

        int kt = t + 2;
        if (kt < NT) {
            int sb = cb + 2; if (sb >= 3) sb -= 3;
            __bf16* sp = lds + sb * 8192;
            int ko = kt * 32;
            gl16(ag[0] + ko, sp + sdA0);
            gl16(ag[1] + ko, sp + sdA1);
            gl16(bg[0] + ko, sp + sdB0);
            gl16(bg[1] + ko, sp + sdB1);
        }

        asm volatile("s_waitcnt lgkmcnt(0)" ::: "memory");
        __builtin_amdgcn_sched_barrier(0);
        __builtin_amdgcn_s_setprio(1);
#pragma unroll
        for (int mi = 0; mi < 4; mi++)
#pragma unroll
            for (int ni = 0; ni < 4; ni++)
                acc[mi][ni] = __builtin_amdgcn_mfma_f32_16x16x32_bf16(a[mi], b[ni], acc[mi][ni], 0, 0, 0);
        __builtin_amdgcn_s_setprio(0);

        if (t < NT - 2)       { asm volatile("s_waitcnt vmcnt(4)" ::: "memory"); }
        else if (t == NT - 2) { asm volatile("s_waitcnt vmcnt(0)" ::: "memory"); }
        if (t < NT - 1) __builtin_amdgcn_s_barrier();
        cb = cb + 1; if (cb >= 3) cb = 0;
    }

#pragma unroll
    for (int mi = 0; mi < 4; mi++) {
#pragma unroll
        for (int ni = 0; ni < 4; ni++) {
            int col = wc * 64 + ni * 16 + cl;
#pragma unroll
            for (int j = 0; j < 4; j++) {
                int row = wr * 64 + mi * 16 + cq * 4 + j;
                y[(size_t)(rb + row) * EMB + n0 + col] = (__bf16)acc[mi][ni][j];
            }
        }
    }
}

extern "C" void kernel_launch(void* const* d_in, const int* in_sizes, int n_in,
                              void* d_out, int out_size, void* d_ws, size_t ws_size,
                              hipStream_t stream)
{
    const float* x   = (const float*)d_in[0];
    const float* gW  = (const float*)d_in[1];
    const float* gb  = (const float*)d_in[2];
    const float* W1  = (const float*)d_in[3];
    const float* b1  = (const float*)d_in[4];
    const float* W2  = (const float*)d_in[5];
    const float* b2  = (const float*)d_in[6];
    float* out = (float*)d_out;

    char* ws = (char*)d_ws;
    int*   counts  = (int*)(ws + WS_COUNTS);
    int*   cursors = (int*)(ws + WS_CURSORS);
    float* ssum    = (float*)(ws + WS_SSUM);
    int*   cellb   = (int*)(ws + WS_CELLB);
    int*   ntiles  = (int*)(ws + WS_NTILES);
    int*   base    = (int*)(ws + WS_BASE);
    int*   tile_e  = (int*)(ws + WS_TILE_E);
    int*   tile_rb = (int*)(ws + WS_TILE_RB);
    int*   tk_idx  = (int*)(ws + WS_TKIDX);
    float* tk_w    = (float*)(ws + WS_TKW);
    int*   slot_of = (int*)(ws + WS_SLOT);
    int*   token_id= (int*)(ws + WS_TOKID);
    float* roww    = (float*)(ws + WS_ROWW);

    __bf16* W1T  = (__bf16*)(ws + WS_BIG2);
    __bf16* xb   = (__bf16*)(ws + WS_BIG2 + SZ_W1T);
    __bf16* W2T  = (__bf16*)(ws + WS_BIG2 + SZ_W1T + SZ_XB);
    __bf16* hbuf = (__bf16*)(ws + WS_BIG2 + SZ_W1T + SZ_XB + SZ_W2T);
    size_t fixedend = WS_BIG2 + SZ_W1T + SZ_XB + SZ_W2T;

    __bf16* y0 = (__bf16*)(ws + WS_BIG2);            // aliases W1T+xb (dead after gemm1)
    __bf16* xg = (__bf16*)(ws + fixedend + SZ_H);
    bool packed = (ws_size >= fixedend + SZ_H + SZ_XG);
    __bf16* y1 = (__bf16*)(ws + fixedend + SZ_H + (packed ? SZ_XG : 0));
    int nsplit = (ws_size >= fixedend + SZ_H + (packed ? SZ_XG : 0) + SZ_Y2) ? 2 : 1;

    hipFuncSetAttribute((const void*)gemm1_8p<true>,  hipFuncAttributeMaxDynamicSharedMemorySize, 49152);
    hipFuncSetAttribute((const void*)gemm1_8p<false>, hipFuncAttributeMaxDynamicSharedMemorySize, 49152);
    hipFuncSetAttribute((const void*)gemm2_128, hipFuncAttributeMaxDynamicSharedMemorySize, 49152);

    hipMemsetAsync(ws + WS_COUNTS, 0, 3072, stream);           // counts+cursors+ssum
    hipMemsetAsync(ws + WS_TOKID, 0xFF, (size_t)MAXROWS * 4, stream);

    transpose_cvt2_kernel<<<16384, 256, 0, stream>>>(W1, W1T, W2, W2T);

    gate_kernel<<<TTOK / 4, 256, 0, stream>>>(x, gW, gb, counts, ssum, tk_idx, tk_w, xb);
    route_build_kernel<<<1, 256, 0, stream>>>(counts, ssum, ntiles, base, tile_e, tile_rb,
                                              cellb, out + (size_t)TTOK * EMB);
    scatter_kernel<<<TTOK / 256, 256, 0, stream>>>(tk_idx, tk_w, cellb, cursors, token_id, roww, slot_of);

    if (packed) {
        pack_x_kernel<<<MAXROWS / 2, 256, 0, stream>>>(xb, token_id, xg);
        gemm1_8p<true><<<8 * 18 * 32, 256, 49152, stream>>>(
            xg, W1T, b1, token_id, tile_e, tile_rb, ntiles, hbuf);
    } else {
        gemm1_8p<false><<<8 * 18 * 32, 256, 49152, stream>>>(
            xb, W1T, b1, token_id, tile_e, tile_rb, ntiles, hbuf);
    }
    gemm2_128<<<8 * 144 * nsplit, 256, 49152, stream>>>(
        hbuf, W2T, tile_e, tile_rb, ntiles, y0, y1, nsplit);
    combine_kernel<<<TTOK, 256, 0, stream>>>(y0, y1, nsplit, slot_of, tk_idx, tk_w, b2, out);
}

// Round 18
// 610.269 us; speedup vs baseline: 1.1264x; 1.0177x over previous
//
#include <hip/hip_runtime.h>
#include <math.h>

#define EMB 1024
#define FF  4096
#define NE  8
#define TTOK 8192

typedef __attribute__((ext_vector_type(4))) float  f32x4;
typedef __attribute__((ext_vector_type(8))) __bf16 bf16x8;
typedef __attribute__((ext_vector_type(4))) __bf16 bf16x4;

#define MAXROWS  18432   // 16384 assignments + 8*256 padding

// ---- ws layout (bytes) ----
#define WS_COUNTS  0        // int[256]
#define WS_CURSORS 1024     // int[256] (sharded)
#define WS_SSUM    2048     // float[256]
#define WS_CELLB   3072     // int[256] per-cell slot bases
#define WS_NTILES  4096
#define WS_BASE    4100
#define WS_TILE_E  4160     // int[160]
#define WS_TILE_RB 4800     // int[160]
#define WS_TKIDX   8192     // int[2*TTOK]
#define WS_TKW     73728    // float[2*TTOK]
#define WS_SLOT    139264   // int[2*TTOK]
#define WS_TOKID   204800   // int[MAXROWS]
#define WS_ROWW    278528   // float[MAXROWS]
#define WS_BIG2    352256   // [W1T | xb | W2T | h | xg | (y1)]

#define SZ_W1T ((size_t)NE * EMB * FF * 2)   // 64 MB
#define SZ_W2T ((size_t)NE * EMB * FF * 2)   // 64 MB
#define SZ_XB  ((size_t)TTOK * EMB * 2)      // 16 MB
#define SZ_H   ((size_t)MAXROWS * FF * 2)    // 144 MB
#define SZ_XG  ((size_t)MAXROWS * EMB * 2)   // 36 MB
#define SZ_Y2  ((size_t)MAXROWS * EMB * 2)   // 36 MB (bf16 y)

__device__ inline f32x4 fzero() { f32x4 v = {0.f, 0.f, 0.f, 0.f}; return v; }

__device__ __forceinline__ void gl16(const void* g, void* l) {
    __builtin_amdgcn_global_load_lds(
        (const __attribute__((address_space(1))) void*)g,
        (__attribute__((address_space(3))) void*)l, 16, 0, 0);
}

// compiler-invisible LDS read: ds_read_b128 at 32-bit LDS byte addr + literal imm
#define DSR(dst, addr, off) \
    asm volatile("ds_read_b128 %0, %1 offset:" #off : "=v"(dst) : "v"(addr))

// fast erf-gelu (A&S 7.1.25, |erf err| <= 5e-4; bf16 h quantization dominates)
__device__ __forceinline__ float gelu_f(float v) {
    float u = fabsf(v) * 0.70710678118654752f;
    float p = 1.0f + u * (0.278393f + u * (0.230389f + u * (0.000972f + u * 0.078108f)));
    p = p * p; p = p * p;
    float er = 1.0f - 1.0f / p;
    float s = (v >= 0.0f) ? er : -er;
    return 0.5f * v * (1.0f + s);
}

// ============================================================================
// fused pre-pass: blocks [0, 16384) = weight transpose+cvt (W1 / W2);
// blocks [16384, 18432) = gating (+ xb emit). The halves are independent
// (disjoint writes, no data flow), so fusion only removes launch serialization.
// ============================================================================
__global__ __launch_bounds__(256) void prepass_kernel(
    const float* __restrict__ W1, __bf16* __restrict__ W1T,
    const float* __restrict__ W2, __bf16* __restrict__ W2T,
    const float* __restrict__ x, const float* __restrict__ gW, const float* __restrict__ gb,
    int* counts, float* ssum, int* tk_idx, float* tk_w, __bf16* __restrict__ xb)
{
    __shared__ __bf16 Ls[64 * 72];   // used only by transpose half
    if (blockIdx.x < 16384) {
        // ---------- transpose+cvt (verbatim r17 transpose_cvt2 body) ----------
        int f = blockIdx.x;
        int which = f >> 13; f &= 8191;
        int e = f >> 10; f &= 1023;
        int R, C, bx, by;
        const float* src; __bf16* dst;
        if (which == 0) { R = EMB; C = FF;  bx = f & 15; by = f >> 4; src = W1; dst = W1T; }
        else            { R = FF;  C = EMB; bx = f & 63; by = f >> 6; src = W2; dst = W2T; }
        src += (size_t)e * R * C;
        dst += (size_t)e * R * C;
        int t = threadIdx.x;
        int r0 = bx * 64, c0 = by * 64;
        int ri = t >> 4, cj = (t & 15) * 4;
#pragma unroll
        for (int p = 0; p < 4; p++) {
            int r = ri + p * 16;
            f32x4 v = *(const f32x4*)(src + (size_t)(r0 + r) * C + c0 + cj);
#pragma unroll
            for (int q = 0; q < 4; q++) Ls[(cj + q) * 72 + r] = (__bf16)v[q];
        }
        __syncthreads();
        int c = t >> 2, rq = (t & 3) * 16;
        bf16x8 a = *(bf16x8*)&Ls[c * 72 + rq];
        bf16x8 b = *(bf16x8*)&Ls[c * 72 + rq + 8];
        *(bf16x8*)(dst + (size_t)(c0 + c) * R + r0 + rq) = a;
        *(bf16x8*)(dst + (size_t)(c0 + c) * R + r0 + rq + 8) = b;
        return;
    }

    // ---------- gating (verbatim r17 gate body; blk = blockIdx.x - 16384) ----------
    int blk = blockIdx.x - 16384;
    int wave = threadIdx.x >> 6;
    int lane = threadIdx.x & 63;
    int t = blk * 4 + wave;

    float acc[NE];
#pragma unroll
    for (int e = 0; e < NE; e++) acc[e] = 0.f;

    const float* xr = x + (size_t)t * EMB;
    __bf16* xbr = xb + (size_t)t * EMB;
#pragma unroll
    for (int i = 0; i < 4; i++) {
        int d0 = i * 256 + lane * 4;
        f32x4 xv = *(const f32x4*)(xr + d0);
        bf16x4 cv;
#pragma unroll
        for (int q = 0; q < 4; q++) cv[q] = (__bf16)xv[q];
        *(bf16x4*)(xbr + d0) = cv;
#pragma unroll
        for (int j = 0; j < 4; j++) {
            const float* wrow = gW + (size_t)(d0 + j) * NE;
            float xs = xv[j];
#pragma unroll
            for (int e = 0; e < NE; e++) acc[e] += xs * wrow[e];
        }
    }
#pragma unroll
    for (int e = 0; e < NE; e++) {
#pragma unroll
        for (int off = 32; off; off >>= 1) acc[e] += __shfl_xor(acc[e], off, 64);
    }
    if (lane == 0) {
        float sc[NE];
        float m = -1e30f;
        for (int e = 0; e < NE; e++) { sc[e] = acc[e] + gb[e]; m = fmaxf(m, sc[e]); }
        float sum = 0.f;
        for (int e = 0; e < NE; e++) { sc[e] = expf(sc[e] - m); sum += sc[e]; }
        float inv = 1.f / sum;
        for (int e = 0; e < NE; e++) sc[e] *= inv;
        int i0 = 0; float s0 = sc[0];
        for (int e = 1; e < NE; e++) if (sc[e] > s0) { s0 = sc[e]; i0 = e; }
        int i1 = -1; float s1 = -1e30f;
        for (int e = 0; e < NE; e++) if (e != i0 && sc[e] > s1) { s1 = sc[e]; i1 = e; }
        float rn = 1.f / (s0 + s1);
        tk_idx[2 * t]     = i0;  tk_idx[2 * t + 1] = i1;
        tk_w[2 * t]       = s0 * rn;  tk_w[2 * t + 1] = s1 * rn;
        int slot = blk & 31;
        atomicAdd(&counts[i0 * 32 + slot], 1);
        atomicAdd(&counts[i1 * 32 + slot], 1);
        for (int e = 0; e < NE; e++) atomicAdd(&ssum[e * 32 + slot], sc[e]);
    }
}

// ---------------- routing tables + per-cell bases + aux (parallel) ----------------
__global__ __launch_bounds__(256) void route_build_kernel(
    const int* counts, const float* ssum,
    int* ntiles, int* base, int* tile_e, int* tile_rb, int* cellbase,
    float* out_aux)
{
    int tid = threadIdx.x;
    int e = tid >> 5, s = tid & 31;
    int c = counts[tid];
    float ss = ssum[tid];

    int inc = c;
#pragma unroll
    for (int d = 1; d < 32; d <<= 1) {
        int t2 = __shfl_up(inc, d, 32);
        if (s >= d) inc += t2;
    }
    float sr = ss;
#pragma unroll
    for (int d = 1; d < 32; d <<= 1) {
        float t2 = __shfl_up(sr, d, 32);
        if (s >= d) sr += t2;
    }

    __shared__ int ctot[NE];
    __shared__ float sstot[NE];
    __shared__ int ebase[NE];
    if (s == 31) { ctot[e] = inc; sstot[e] = sr; }
    __syncthreads();

    if (tid == 0) {
        int total = 0, tiles = 0;
        float aux = 0.f;
        for (int ee = 0; ee < NE; ee++) {
            ebase[ee] = total;
            int nt = (ctot[ee] + 255) >> 8;
            for (int i = 0; i < nt; i++) { tile_e[tiles] = ee; tile_rb[tiles] = total + (i << 8); tiles++; }
            total += nt << 8;
            aux += ((float)ctot[ee] / (float)(TTOK * 2)) * (sstot[ee] / (float)TTOK);
        }
        *ntiles = tiles;
        *out_aux = aux * (float)NE;
    }
    __syncthreads();
    cellbase[tid] = ebase[e] + (inc - c);
    if (s == 0) base[e] = ebase[e];
}

// ---------------- scatter: sharded cursors (cell = e*32 + (t>>2)&31) ----------------
__global__ __launch_bounds__(256) void scatter_kernel(
    const int* __restrict__ tk_idx, const float* __restrict__ tk_w,
    const int* __restrict__ cellbase, int* cursors, int* token_id, float* roww,
    int* slot_of)
{
    int t = blockIdx.x * 256 + threadIdx.x;
    int shard = (t >> 2) & 31;
#pragma unroll
    for (int k = 0; k < 2; k++) {
        int e = tk_idx[2 * t + k];
        int cell = e * 32 + shard;
        int pos = atomicAdd(&cursors[cell], 1);
        int slot = cellbase[cell] + pos;
        token_id[slot] = t;
        roww[slot] = tk_w[2 * t + k];
        slot_of[2 * t + k] = slot;
    }
}

// ---------------- pack: xg[slot] = xb[token_id[slot]] (0 for pad) ----------------
__global__ __launch_bounds__(256) void pack_x_kernel(
    const __bf16* __restrict__ xb, const int* __restrict__ token_id,
    __bf16* __restrict__ xg)
{
    int tid = threadIdx.x;
    int slot = blockIdx.x * 2 + (tid >> 7);
    int off = (tid & 127) * 8;
    int tok = token_id[slot];
    uint4 v = {0u, 0u, 0u, 0u};
    if (tok >= 0) v = *(const uint4*)(xb + (size_t)tok * EMB + off);
    *(uint4*)(xg + (size_t)slot * EMB + off) = v;
}

// ---------------- combine (y in bf16) ----------------
__global__ __launch_bounds__(256) void combine_kernel(
    const __bf16* __restrict__ y0, const __bf16* __restrict__ y1, int nsplit,
    const int* __restrict__ slot_of,
    const int* __restrict__ tk_idx, const float* __restrict__ tk_w,
    const float* __restrict__ b2, float* __restrict__ out)
{
    int t = blockIdx.x;
    int dq = threadIdx.x * 4;
    int s0 = slot_of[2 * t], s1 = slot_of[2 * t + 1];
    int e0 = tk_idx[2 * t], e1 = tk_idx[2 * t + 1];
    float w0 = tk_w[2 * t], w1 = tk_w[2 * t + 1];
    bf16x4 va = *(const bf16x4*)(y0 + (size_t)s0 * EMB + dq);
    bf16x4 vb = *(const bf16x4*)(y0 + (size_t)s1 * EMB + dq);
    f32x4 ya, yb;
#pragma unroll
    for (int q = 0; q < 4; q++) { ya[q] = (float)va[q]; yb[q] = (float)vb[q]; }
    if (nsplit == 2) {
        bf16x4 za = *(const bf16x4*)(y1 + (size_t)s0 * EMB + dq);
        bf16x4 zb = *(const bf16x4*)(y1 + (size_t)s1 * EMB + dq);
#pragma unroll
        for (int q = 0; q < 4; q++) { ya[q] += (float)za[q]; yb[q] += (float)zb[q]; }
    }
    f32x4 ba = *(const f32x4*)(b2 + (size_t)e0 * EMB + dq);
    f32x4 bb = *(const f32x4*)(b2 + (size_t)e1 * EMB + dq);
    f32x4 r;
#pragma unroll
    for (int q = 0; q < 4; q++) r[q] = w0 * (ya[q] + ba[q]) + w1 * (yb[q] + bb[q]);
    *(f32x4*)(out + (size_t)t * EMB + dq) = r;
}

// ============================================================================
// gemm1 (r15/16/17 green): BM=128, BN=128, BK=32, 256 thr (4 waves 2x2, wave
// tile 64x64, acc[4][4]). 3 LDS bufs x 16KB = 48KB -> 3 blocks/CU, 3
// independent barrier domains. L2-blocked grid: nbg outer (4 groups of 8),
// sti middle, nbi inner. Counted vmcnt(4), XOR chunk swizzle, 0 conflicts.
// ============================================================================

template <bool PACKED>
__global__ __launch_bounds__(256, 3) void gemm1_8p(
    const __bf16* __restrict__ xsrc, const __bf16* __restrict__ W1T,
    const float* __restrict__ b1,
    const int* __restrict__ token_id, const int* __restrict__ tile_e,
    const int* __restrict__ tile_rb, const int* __restrict__ ntiles,
    __bf16* __restrict__ h)
{
    extern __shared__ __bf16 lds[];   // 3 bufs x 8192 elems
    int flat = blockIdx.x;
    int c8 = flat & 7, r = flat >> 3;
    int nbg = r / 144;
    int rem = r - nbg * 144;
    int sti = rem >> 3;
    int nb  = (nbg << 3) | (rem & 7);
    int st = c8 * 18 + sti;
    if (st >= *ntiles * 2) return;
    int e = tile_e[st >> 1];
    int rb = tile_rb[st >> 1] + (st & 1) * 128;
    int n0 = nb * 128;

    int tid = threadIdx.x, lane = tid & 63, wid = tid >> 6;
    int wr = wid >> 1, wc = wid & 1;
    int cl = lane & 15, cq = lane >> 4;

    int srow1 = ((tid >> 6) << 4) | ((tid & 63) >> 2);
    int schunk = (tid & 3) ^ ((tid >> 3) & 3);
    const __bf16* ag[2];
#pragma unroll
    for (int hm = 0; hm < 2; hm++) {
        int row = srow1 + hm * 64;
        if (PACKED) {
            ag[hm] = xsrc + (size_t)(rb + row) * EMB + schunk * 8;
        } else {
            int tok = token_id[rb + row];
            if (tok < 0) tok = 0;
            ag[hm] = xsrc + (size_t)tok * EMB + schunk * 8;
        }
    }
    const __bf16* bg[2];
#pragma unroll
    for (int hn = 0; hn < 2; hn++)
        bg[hn] = W1T + ((size_t)e * FF + (size_t)(n0 + srow1 + hn * 64)) * EMB + schunk * 8;

    int sdA0 = wid * 512, sdA1 = 2048 + wid * 512;
    int sdB0 = 4096 + wid * 512, sdB1 = 6144 + wid * 512;

    uint32_t lb = (uint32_t)(uintptr_t)(__attribute__((address_space(3))) __bf16*)lds;
    int xoffe = (cq ^ ((cl >> 1) & 3)) * 8;
    uint32_t ab0 = lb + 2u * (uint32_t)(wr * 2048 + cl * 32 + xoffe);
    uint32_t bb0 = lb + 2u * (uint32_t)(4096 + wc * 2048 + cl * 32 + xoffe);

    f32x4 acc[4][4];
#pragma unroll
    for (int i = 0; i < 4; i++)
#pragma unroll
        for (int j = 0; j < 4; j++) acc[i][j] = fzero();

    const int NT = EMB / 32;
#pragma unroll
    for (int t0 = 0; t0 < 2; t0++) {
        __bf16* bp = lds + t0 * 8192;
        int k0 = t0 * 32;
        gl16(ag[0] + k0, bp + sdA0);
        gl16(ag[1] + k0, bp + sdA1);
        gl16(bg[0] + k0, bp + sdB0);
        gl16(bg[1] + k0, bp + sdB1);
    }
    asm volatile("s_waitcnt vmcnt(4)" ::: "memory");
    __builtin_amdgcn_s_barrier();

    int cb = 0;
#pragma unroll 1
    for (int t = 0; t < NT; t++) {
        uint32_t cboff = (uint32_t)cb * 16384u;
        uint32_t aaddr = ab0 + cboff, baddr = bb0 + cboff;
        bf16x8 b[4], a[4];
        DSR(b[0], baddr, 0);    DSR(b[1], baddr, 1024);
        DSR(b[2], baddr, 2048); DSR(b[3], baddr, 3072);
        DSR(a[0], aaddr, 0);    DSR(a[1], aaddr, 1024);
        DSR(a[2], aaddr, 2048); DSR(a[3], aaddr, 3072);

        int kt = t + 2;
        if (kt < NT) {
            int sb = cb + 2; if (sb >= 3) sb -= 3;
            __bf16* sp = lds + sb * 8192;
            int ko = kt * 32;
            gl16(ag[0] + ko, sp + sdA0);
            gl16(ag[1] + ko, sp + sdA1);
            gl16(bg[0] + ko, sp + sdB0);
            gl16(bg[1] + ko, sp + sdB1);
        }

        asm volatile("s_waitcnt lgkmcnt(0)" ::: "memory");
        __builtin_amdgcn_sched_barrier(0);
        __builtin_amdgcn_s_setprio(1);
#pragma unroll
        for (int mi = 0; mi < 4; mi++)
#pragma unroll
            for (int ni = 0; ni < 4; ni++)
                acc[mi][ni] = __builtin_amdgcn_mfma_f32_16x16x32_bf16(a[mi], b[ni], acc[mi][ni], 0, 0, 0);
        __builtin_amdgcn_s_setprio(0);

        if (t < NT - 2)       { asm volatile("s_waitcnt vmcnt(4)" ::: "memory"); }
        else if (t == NT - 2) { asm volatile("s_waitcnt vmcnt(0)" ::: "memory"); }
        if (t < NT - 1) __builtin_amdgcn_s_barrier();
        cb = cb + 1; if (cb >= 3) cb = 0;
    }

    const float* b1g = b1 + (size_t)e * FF + n0;
#pragma unroll
    for (int mi = 0; mi < 4; mi++) {
#pragma unroll
        for (int ni = 0; ni < 4; ni++) {
            int col = wc * 64 + ni * 16 + cl;
            float bias = b1g[col];
#pragma unroll
            for (int j = 0; j < 4; j++) {
                int row = wr * 64 + mi * 16 + cq * 4 + j;
                float v = acc[mi][ni][j] + bias;
                h[(size_t)(rb + row) * FF + n0 + col] = (__bf16)gelu_f(v);
            }
        }
    }
}

// ============================================================================
// gemm2 (r16/17 green): same structure; L2-blocked grid per XCD:
// z outer, nbg (2 groups of 4 n-panels), sti middle, nbi inner.
// ============================================================================
__global__ __launch_bounds__(256, 3) void gemm2_128(
    const __bf16* __restrict__ h, const __bf16* __restrict__ W2T,
    const int* __restrict__ tile_e, const int* __restrict__ tile_rb,
    const int* __restrict__ ntiles,
    __bf16* __restrict__ y0, __bf16* __restrict__ y1, int nsplit)
{
    extern __shared__ __bf16 lds[];
    int flat = blockIdx.x;
    int c8 = flat & 7, r = flat >> 3;
    int z = r / 144;
    int rem = r - z * 144;
    int nbg = rem / 72;
    int rem2 = rem - nbg * 72;
    int sti = rem2 >> 2, nbi = rem2 & 3;
    int nb = (nbg << 2) | nbi;
    int st = c8 * 18 + sti;
    if (st >= *ntiles * 2) return;
    int e = tile_e[st >> 1];
    int rb = tile_rb[st >> 1] + (st & 1) * 128;
    int n0 = nb * 128;
    int KC = FF / nsplit;
    int koff = z * KC;
    __bf16* y = z ? y1 : y0;

    int tid = threadIdx.x, lane = tid & 63, wid = tid >> 6;
    int wr = wid >> 1, wc = wid & 1;
    int cl = lane & 15, cq = lane >> 4;

    int srow1 = ((tid >> 6) << 4) | ((tid & 63) >> 2);
    int schunk = (tid & 3) ^ ((tid >> 3) & 3);
    const __bf16* ag[2];
#pragma unroll
    for (int hm = 0; hm < 2; hm++)
        ag[hm] = h + (size_t)(rb + srow1 + hm * 64) * FF + koff + schunk * 8;
    const __bf16* bg[2];
#pragma unroll
    for (int hn = 0; hn < 2; hn++)
        bg[hn] = W2T + ((size_t)e * EMB + (size_t)(n0 + srow1 + hn * 64)) * FF + koff + schunk * 8;

    int sdA0 = wid * 512, sdA1 = 2048 + wid * 512;
    int sdB0 = 4096 + wid * 512, sdB1 = 6144 + wid * 512;

    uint32_t lb = (uint32_t)(uintptr_t)(__attribute__((address_space(3))) __bf16*)lds;
    int xoffe = (cq ^ ((cl >> 1) & 3)) * 8;
    uint32_t ab0 = lb + 2u * (uint32_t)(wr * 2048 + cl * 32 + xoffe);
    uint32_t bb0 = lb + 2u * (uint32_t)(4096 + wc * 2048 + cl * 32 + xoffe);

    f32x4 acc[4][4];
#pragma unroll
    for (int i = 0; i < 4; i++)
#pragma unroll
        for (int j = 0; j < 4; j++) acc[i][j] = fzero();

    const int NT = KC / 32;
#pragma unroll
    for (int t0 = 0; t0 < 2; t0++) {
        __bf16* bp = lds + t0 * 8192;
        int k0 = t0 * 32;
        gl16(ag[0] + k0, bp + sdA0);
        gl16(ag[1] + k0, bp + sdA1);
        gl16(bg[0] + k0, bp + sdB0);
        gl16(bg[1] + k0, bp + sdB1);
    }
    asm volatile("s_waitcnt vmcnt(4)" ::: "memory");
    __builtin_amdgcn_s_barrier();

    int cb = 0;
#pragma unroll 1
    for (int t = 0; t < NT; t++) {
        uint32_t cboff = (uint32_t)cb * 16384u;
        uint32_t aaddr = ab0 + cboff, baddr = bb0 + cboff;
        bf16x8 b[4], a[4];
        DSR(b[0], baddr, 0);    DSR(b[1], baddr, 1024);
        DSR(b[2], baddr, 2048); DSR(b[3], baddr, 3072);
        DSR(a[0], aaddr, 0);    DSR(a[1], aaddr, 1024);
        DSR(a[2], aaddr, 2048); DSR(a[3], aaddr, 3072);

        int kt = t + 2;
        if (kt < NT) {
            int sb = cb + 2; if (sb >= 3) sb -= 3;
            __bf16* sp = lds + sb * 8192;
            int ko = kt * 32;
            gl16(ag[0] + ko, sp + sdA0);
            gl16(ag[1] + ko, sp + sdA1);
            gl16(bg[0] + ko, sp + sdB0);
            gl16(bg[1] + ko, sp + sdB1);
        }

        asm volatile("s_waitcnt lgkmcnt(0)" ::: "memory");
        __builtin_amdgcn_sched_barrier(0);
        __builtin_amdgcn_s_setprio(1);
#pragma unroll
        for (int mi = 0; mi < 4; mi++)
#pragma unroll
            for (int ni = 0; ni < 4; ni++)
                acc[mi][ni] = __builtin_amdgcn_mfma_f32_16x16x32_bf16(a[mi], b[ni], acc[mi][ni], 0, 0, 0);
        __builtin_amdgcn_s_setprio(0);

        if (t < NT - 2)       { asm volatile("s_waitcnt vmcnt(4)" ::: "memory"); }
        else if (t == NT - 2) { asm volatile("s_waitcnt vmcnt(0)" ::: "memory"); }
        if (t < NT - 1) __builtin_amdgcn_s_barrier();
        cb = cb + 1; if (cb >= 3) cb = 0;
    }

#pragma unroll
    for (int mi = 0; mi < 4; mi++) {
#pragma unroll
        for (int ni = 0; ni < 4; ni++) {
            int col = wc * 64 + ni * 16 + cl;
#pragma unroll
            for (int j = 0; j < 4; j++) {
                int row = wr * 64 + mi * 16 + cq * 4 + j;
                y[(size_t)(rb + row) * EMB + n0 + col] = (__bf16)acc[mi][ni][j];
            }
        }
    }
}

extern "C" void kernel_launch(void* const* d_in, const int* in_sizes, int n_in,
                              void* d_out, int out_size, void* d_ws, size_t ws_size,
                              hipStream_t stream)
{
    const float* x   = (const float*)d_in[0];
    const float* gW  = (const float*)d_in[1];
    const float* gb  = (const float*)d_in[2];
    const float* W1  = (const float*)d_in[3];
    const float* b1  = (const float*)d_in[4];
    const float* W2  = (const float*)d_in[5];
    const float* b2  = (const float*)d_in[6];
    float* out = (float*)d_out;

    char* ws = (char*)d_ws;
    int*   counts  = (int*)(ws + WS_COUNTS);
    int*   cursors = (int*)(ws + WS_CURSORS);
    float* ssum    = (float*)(ws + WS_SSUM);
    int*   cellb   = (int*)(ws + WS_CELLB);
    int*   ntiles  = (int*)(ws + WS_NTILES);
    int*   base    = (int*)(ws + WS_BASE);
    int*   tile_e  = (int*)(ws + WS_TILE_E);
    int*   tile_rb = (int*)(ws + WS_TILE_RB);
    int*   tk_idx  = (int*)(ws + WS_TKIDX);
    float* tk_w    = (float*)(ws + WS_TKW);
    int*   slot_of = (int*)(ws + WS_SLOT);
    int*   token_id= (int*)(ws + WS_TOKID);
    float* roww    = (float*)(ws + WS_ROWW);

    __bf16* W1T  = (__bf16*)(ws + WS_BIG2);
    __bf16* xb   = (__bf16*)(ws + WS_BIG2 + SZ_W1T);
    __bf16* W2T  = (__bf16*)(ws + WS_BIG2 + SZ_W1T + SZ_XB);
    __bf16* hbuf = (__bf16*)(ws + WS_BIG2 + SZ_W1T + SZ_XB + SZ_W2T);
    size_t fixedend = WS_BIG2 + SZ_W1T + SZ_XB + SZ_W2T;

    __bf16* y0 = (__bf16*)(ws + WS_BIG2);            // aliases W1T+xb (dead after gemm1)
    __bf16* xg = (__bf16*)(ws + fixedend + SZ_H);
    bool packed = (ws_size >= fixedend + SZ_H + SZ_XG);
    __bf16* y1 = (__bf16*)(ws + fixedend + SZ_H + (packed ? SZ_XG : 0));
    int nsplit = (ws_size >= fixedend + SZ_H + (packed ? SZ_XG : 0) + SZ_Y2) ? 2 : 1;

    hipFuncSetAttribute((const void*)gemm1_8p<true>,  hipFuncAttributeMaxDynamicSharedMemorySize, 49152);
    hipFuncSetAttribute((const void*)gemm1_8p<false>, hipFuncAttributeMaxDynamicSharedMemorySize, 49152);
    hipFuncSetAttribute((const void*)gemm2_128, hipFuncAttributeMaxDynamicSharedMemorySize, 49152);

    hipMemsetAsync(ws + WS_COUNTS, 0, 3072, stream);           // counts+cursors+ssum
    hipMemsetAsync(ws + WS_TOKID, 0xFF, (size_t)MAXROWS * 4, stream);

    prepass_kernel<<<16384 + TTOK / 4, 256, 0, stream>>>(
        W1, W1T, W2, W2T, x, gW, gb, counts, ssum, tk_idx, tk_w, xb);
    route_build_kernel<<<1, 256, 0, stream>>>(counts, ssum, ntiles, base, tile_e, tile_rb,
                                              cellb, out + (size_t)TTOK * EMB);
    scatter_kernel<<<TTOK / 256, 256, 0, stream>>>(tk_idx, tk_w, cellb, cursors, token_id, roww, slot_of);

    if (packed) {
        pack_x_kernel<<<MAXROWS / 2, 256, 0, stream>>>(xb, token_id, xg);
        gemm1_8p<true><<<8 * 18 * 32, 256, 49152, stream>>>(
            xg, W1T, b1, token_id, tile_e, tile_rb, ntiles, hbuf);
    } else {
        gemm1_8p<false><<<8 * 18 * 32, 256, 49152, stream>>>(
            xb, W1T, b1, token_id, tile_e, tile_rb, ntiles, hbuf);
    }
    gemm2_128<<<8 * 144 * nsplit, 256, 49152, stream>>>(
        hbuf, W2T, tile_e, tile_rb, ntiles, y0, y1, nsplit);
    combine_kernel<<<TTOK, 256, 0, stream>>>(y0, y1, nsplit, slot_of, tk_idx, tk_w, b2, out);
}